// Round 7
// baseline (337.801 us; speedup 1.0000x reference)
//
#include <hip/hip_runtime.h>
#include <math.h>

typedef __bf16 bf16x8 __attribute__((ext_vector_type(8)));
typedef float f32x4 __attribute__((ext_vector_type(4)));
typedef unsigned short u16x8 __attribute__((ext_vector_type(8)));
typedef unsigned short u16x4v __attribute__((ext_vector_type(4)));

__device__ __forceinline__ unsigned short f2bf(float f){
  unsigned u = __builtin_bit_cast(unsigned, f);
  u += 0x7fffu + ((u>>16)&1u);
  return (unsigned short)(u>>16);
}
__device__ __forceinline__ unsigned pack2(float a, float b){
  return (unsigned)f2bf(a) | ((unsigned)f2bf(b)<<16);
}
__device__ __forceinline__ float bf2f(unsigned short h){
  unsigned u = ((unsigned)h)<<16;
  return __builtin_bit_cast(float, u);
}
__device__ __forceinline__ bf16x8 ldfrag_g(const unsigned short* p){
  u16x8 v = *reinterpret_cast<const u16x8*>(p);
  return __builtin_bit_cast(bf16x8, v);
}
__device__ __forceinline__ f32x4 mfma16(bf16x8 a, bf16x8 b, f32x4 c){
  return __builtin_amdgcn_mfma_f32_16x16x32_bf16(a, b, c, 0, 0, 0);
}

// ============ k0: weights fp32 -> bf16 MFMA fragment layout (+ tap repack) ============
__global__ __launch_bounds__(64) void k0_wfrag(
  const float* __restrict__ Wk, const float* __restrict__ Wq,
  const float* __restrict__ Wv, const float* __restrict__ Wr,
  const float* __restrict__ W1, const float* __restrict__ W2,
  const float* __restrict__ dww, const float* __restrict__ dwb,
  float* __restrict__ dwp, unsigned short* __restrict__ wf)
{
  const int bid = blockIdx.x, l = threadIdx.x;
  if (bid == 96){
    // taps+bias, natural channel order: dwp[c*12 + j] (j=0..8 taps, 9=bias)
    #pragma unroll
    for (int cc=0;cc<4;++cc){
      int c = l*4 + cc;
      #pragma unroll
      for (int j=0;j<9;++j) dwp[c*12 + j] = dww[c*9+j];
      dwp[c*12 + 9]  = dwb[c];
      dwp[c*12 + 10] = 0.f;
      dwp[c*12 + 11] = 0.f;
    }
    return;
  }
  const float* src; int K, nt, ks; unsigned short* dst;
  if (bid < 32){
    int w = bid>>3, f = bid&7;
    src = (w==0)?Wk:(w==1)?Wq:(w==2)?Wv:Wr;
    K = 64; nt = f>>1; ks = f&1;
    dst = wf + w*4096 + f*512;
  } else if (bid < 64){
    int f = bid-32; src = W1; K = 64; nt = f>>1; ks = f&1;
    dst = wf + 16384 + f*512;
  } else {
    int f = bid-64; src = W2; K = 256; nt = f>>3; ks = f&7;
    dst = wf + 32768 + f*512;
  }
  u16x8 v;
  #pragma unroll
  for (int j=0;j<8;++j){
    int k = ks*32 + (l>>4)*8 + j;
    int n = nt*16 + (l&15);
    v[j] = f2bf(src[n*K + k]);
  }
  *reinterpret_cast<u16x8*>(dst + l*8) = v;
}

// ============ k1: LN1 + K/V proj (MFMA) + ctx accumulation (MFMA, LDS-transpose) ============
__global__ __launch_bounds__(256,2) void k1_ctx(
  const float* __restrict__ x, const float* __restrict__ g1, const float* __restrict__ be1,
  const float* __restrict__ bk, const float* __restrict__ bv,
  const unsigned short* __restrict__ wf,
  float* __restrict__ g_part, float* __restrict__ g_sump)
{
  __shared__ unsigned short tiles[4][4096];
  __shared__ float ctx_l[64*68];
  __shared__ float ssum_l[4][64];
  const int t = threadIdx.x, wid = t>>6, l = t&63;
  const int lg = l>>4, l15 = l&15;
  unsigned short* tile = tiles[wid];
  const int tok0 = blockIdx.x*512 + wid*128;

  bf16x8 WkF[8], WvF[8];
  #pragma unroll
  for (int f=0; f<8; ++f){
    WkF[f] = ldfrag_g(wf +    0 + f*512 + l*8);
    WvF[f] = ldfrag_g(wf + 8192 + f*512 + l*8);
  }
  float4 g1v  = *reinterpret_cast<const float4*>(&g1[l15*4]);
  float4 be1v = *reinterpret_cast<const float4*>(&be1[l15*4]);
  float bkv[4], bvv[4];
  #pragma unroll
  for (int ct=0; ct<4; ++ct){ bkv[ct]=bk[ct*16+l15]; bvv[ct]=bv[ct*16+l15]; }

  f32x4 acc[4][4];
  #pragma unroll
  for (int a=0;a<4;++a)
    #pragma unroll
    for (int b=0;b<4;++b) acc[a][b] = (f32x4){0.f,0.f,0.f,0.f};
  float sume[4] = {0.f,0.f,0.f,0.f};

  for (int tb=0; tb<2; ++tb){
    const int tbase = tok0 + tb*64;
    #pragma unroll
    for (int it=0; it<16; ++it){
      int row = it*4 + lg;
      float4 xv = *reinterpret_cast<const float4*>(&x[(size_t)(tbase+row)*64 + l15*4]);
      float s1 = xv.x+xv.y+xv.z+xv.w;
      float s2 = xv.x*xv.x + xv.y*xv.y + xv.z*xv.z + xv.w*xv.w;
      #pragma unroll
      for (int off=1; off<16; off<<=1){ s1 += __shfl_xor(s1,off,64); s2 += __shfl_xor(s2,off,64); }
      float mu = s1*(1.f/64.f);
      float rs = rsqrtf(s2*(1.f/64.f) - mu*mu + 1e-5f);
      uint2 pk = { pack2((xv.x-mu)*rs*g1v.x + be1v.x, (xv.y-mu)*rs*g1v.y + be1v.y),
                   pack2((xv.z-mu)*rs*g1v.z + be1v.z, (xv.w-mu)*rs*g1v.w + be1v.w) };
      *reinterpret_cast<uint2*>(&tile[row*64 + ((l15*4) ^ ((row&7)<<3))]) = pk;
    }
    bf16x8 aF[4][2];
    #pragma unroll
    for (int mt=0;mt<4;++mt){
      int row = mt*16+l15, sw=(row&7)<<3, ab=row*64;
      aF[mt][0] = __builtin_bit_cast(bf16x8, *reinterpret_cast<const u16x8*>(tile+ab+((     lg*8)^sw)));
      aF[mt][1] = __builtin_bit_cast(bf16x8, *reinterpret_cast<const u16x8*>(tile+ab+((32 + lg*8)^sw)));
    }
    #pragma unroll
    for (int half=0; half<2; ++half){
      #pragma unroll
      for (int m2=0;m2<2;++m2){
        const int mt = half*2+m2;
        #pragma unroll
        for (int ct=0;ct<4;++ct){
          f32x4 z = {0.f,0.f,0.f,0.f};
          z = mfma16(aF[mt][0], WkF[ct*2+0], z);
          z = mfma16(aF[mt][1], WkF[ct*2+1], z);
          float e0=__expf(z[0]+bkv[ct]), e1=__expf(z[1]+bkv[ct]);
          float e2=__expf(z[2]+bkv[ct]), e3=__expf(z[3]+bkv[ct]);
          sume[ct] += (e0+e1)+(e2+e3);
          const int c = ct*16+l15, sw = (c&7)<<3;
          const int cb = m2*16+lg*4;
          uint2 pe = { pack2(e0,e1), pack2(e2,e3) };
          *reinterpret_cast<uint2*>(&tile[c*64 + (cb ^ sw)]) = pe;
          f32x4 w = {0.f,0.f,0.f,0.f};
          w = mfma16(aF[mt][0], WvF[ct*2+0], w);
          w = mfma16(aF[mt][1], WvF[ct*2+1], w);
          uint2 pv = { pack2(w[0]+bvv[ct], w[1]+bvv[ct]), pack2(w[2]+bvv[ct], w[3]+bvv[ct]) };
          *reinterpret_cast<uint2*>(&tile[c*64 + ((32+cb) ^ sw)]) = pv;
        }
      }
      bf16x8 eA[4], vB[4];
      #pragma unroll
      for (int cm=0;cm<4;++cm){
        int row = cm*16+l15, sw=(row&7)<<3;
        eA[cm] = __builtin_bit_cast(bf16x8, *reinterpret_cast<const u16x8*>(tile + row*64 + ((     lg*8)^sw)));
        vB[cm] = __builtin_bit_cast(bf16x8, *reinterpret_cast<const u16x8*>(tile + row*64 + ((32 + lg*8)^sw)));
      }
      #pragma unroll
      for (int cm=0; cm<4; ++cm)
        #pragma unroll
        for (int jn=0; jn<4; ++jn)
          acc[cm][jn] = mfma16(eA[cm], vB[jn], acc[cm][jn]);
    }
  }
  #pragma unroll
  for (int ct=0; ct<4; ++ct){
    float s = sume[ct];
    s += __shfl_xor(s,16,64); s += __shfl_xor(s,32,64);
    if (lg==0) ssum_l[wid][ct*16+l15] = s;
  }
  #define CTX_RED(OP) \
    _Pragma("unroll") for (int cm=0;cm<4;++cm) \
    _Pragma("unroll") for (int jn=0;jn<4;++jn) \
    _Pragma("unroll") for (int r=0;r<4;++r) \
      ctx_l[(cm*16+lg*4+r)*68 + jn*16+l15] OP acc[cm][jn][r];
  if (wid==0){ CTX_RED(=) }  __syncthreads();
  if (wid==1){ CTX_RED(+=) } __syncthreads();
  if (wid==2){ CTX_RED(+=) } __syncthreads();
  if (wid==3){ CTX_RED(+=) } __syncthreads();
  #undef CTX_RED
  for (int i=t; i<4096; i+=256)
    g_part[(size_t)blockIdx.x*4096 + i] = ctx_l[(i>>6)*68 + (i&63)];
  if (t<64)
    g_sump[blockIdx.x*64 + t] = ssum_l[0][t]+ssum_l[1][t]+ssum_l[2][t]+ssum_l[3][t];
}

// ============ k15: reduce partials; ctxWr = (ctx_norm @ Wr^T) -> bf16 frags ============
__global__ __launch_bounds__(512) void k15_ctxwr(
  const float* __restrict__ g_part, const float* __restrict__ g_sump,
  const float* __restrict__ Wr, unsigned short* __restrict__ ctxWrF)
{
  __shared__ float sctx[4096];
  __shared__ float sWr[4096];
  __shared__ float sinv[64];
  const int b = blockIdx.x, t = threadIdx.x;
  if (t<64){
    float s=0.f;
    #pragma unroll 8
    for (int p=0;p<32;++p) s += g_sump[(b*32+p)*64 + t];
    sinv[t] = 1.f/s;
  }
  for (int idx=t; idx<4096; idx+=512){
    float s=0.f;
    #pragma unroll 8
    for (int p=0;p<32;++p) s += g_part[(size_t)(b*32+p)*4096 + idx];
    sctx[idx] = s;
  }
  __syncthreads();
  {
    int c = t>>3, d0 = (t&7)*8;
    float invc = sinv[c];
    #pragma unroll
    for (int dd=0; dd<8; ++dd){
      int d = d0+dd; float s = 0.f;
      #pragma unroll
      for (int v=0; v<64; ++v) s += sctx[c*64+v]*Wr[d*64+v];
      sWr[c*64+d] = s*invc;
    }
  }
  __syncthreads();
  {
    int f = t>>6, l = t&63, nt = f>>1, ks = f&1;
    u16x8 v;
    #pragma unroll
    for (int j=0;j<8;++j){
      int k = ks*32 + (l>>4)*8 + j;
      int n = nt*16 + (l&15);
      v[j] = f2bf(sWr[k*64+n]);
    }
    *reinterpret_cast<u16x8*>(ctxWrF + b*4096 + f*512 + l*8) = v;
  }
}

// ============ k2: LN1 + q-softmax + attn + residual + LN2 -> n2 (bf16, wide stores) ============
__global__ __launch_bounds__(256,2) void k2_attn_ffn1(
  const float* __restrict__ x,
  const float* __restrict__ g1, const float* __restrict__ be1,
  const float* __restrict__ bq, const float* __restrict__ br,
  const float* __restrict__ g2, const float* __restrict__ be2,
  const unsigned short* __restrict__ wf,
  const unsigned short* __restrict__ ctxWrF,
  unsigned short* __restrict__ g_txb, unsigned short* __restrict__ n2g)
{
  __shared__ unsigned short tiles[4][4096];
  const int t = threadIdx.x, wid = t>>6, l = t&63;
  const int l15 = l&15, lg = l>>4;
  unsigned short* tile = tiles[wid];
  const int tok0 = (blockIdx.x*4 + wid)*64;
  const int img  = blockIdx.x>>6;

  bf16x8 WqF[8], CWF[8];
  #pragma unroll
  for (int f=0; f<8; ++f){
    WqF[f] = ldfrag_g(wf + 4096 + f*512 + l*8);
    CWF[f] = ldfrag_g(ctxWrF + img*4096 + f*512 + l*8);
  }
  float4 g1v  = *reinterpret_cast<const float4*>(&g1[l15*4]);
  float4 be1v = *reinterpret_cast<const float4*>(&be1[l15*4]);
  float bqv[4], brv[4], g2v[4], be2v[4];
  #pragma unroll
  for (int nt=0; nt<4; ++nt){
    bqv[nt]=bq[nt*16+l15]; brv[nt]=br[nt*16+l15];
    g2v[nt]=g2[nt*16+l15]; be2v[nt]=be2[nt*16+l15];
  }

  // ---- LN1 -> swizzled bf16 tile ----
  #pragma unroll
  for (int it=0; it<16; ++it){
    int row = it*4 + lg;
    float4 xv = *reinterpret_cast<const float4*>(&x[(size_t)(tok0+row)*64 + l15*4]);
    float s1 = xv.x+xv.y+xv.z+xv.w;
    float s2 = xv.x*xv.x + xv.y*xv.y + xv.z*xv.z + xv.w*xv.w;
    #pragma unroll
    for (int off=1; off<16; off<<=1){ s1 += __shfl_xor(s1,off,64); s2 += __shfl_xor(s2,off,64); }
    float mu = s1*(1.f/64.f);
    float rs = rsqrtf(s2*(1.f/64.f) - mu*mu + 1e-5f);
    uint2 pk = { pack2((xv.x-mu)*rs*g1v.x + be1v.x, (xv.y-mu)*rs*g1v.y + be1v.y),
                 pack2((xv.z-mu)*rs*g1v.z + be1v.z, (xv.w-mu)*rs*g1v.w + be1v.w) };
    *reinterpret_cast<uint2*>(&tile[row*64 + ((l15*4) ^ ((row&7)<<3))]) = pk;
  }

  // ---- phase A: per m-tile attn chain; leaves n2 in the tile ----
  for (int mt=0; mt<4; ++mt){
    const int arow = mt*16 + l15;
    const int asw  = (arow&7)<<3;
    const int abase= arow*64;
    bf16x8 a0 = __builtin_bit_cast(bf16x8, *reinterpret_cast<const u16x8*>(tile + abase + ((     lg*8) ^ asw)));
    bf16x8 a1 = __builtin_bit_cast(bf16x8, *reinterpret_cast<const u16x8*>(tile + abase + ((32 + lg*8) ^ asw)));
    f32x4 qa[4];
    #pragma unroll
    for (int nt=0; nt<4; ++nt){
      f32x4 z = {0.f,0.f,0.f,0.f};
      z = mfma16(a0, WqF[nt*2+0], z);
      z = mfma16(a1, WqF[nt*2+1], z);
      qa[nt] = z;
    }
    #pragma unroll
    for (int nt=0; nt<4; ++nt)
      #pragma unroll
      for (int r=0; r<4; ++r) qa[nt][r] += bqv[nt];
    float mx[4];
    #pragma unroll
    for (int r=0;r<4;++r) mx[r] = fmaxf(fmaxf(qa[0][r],qa[1][r]), fmaxf(qa[2][r],qa[3][r]));
    #pragma unroll
    for (int off=1; off<16; off<<=1)
      #pragma unroll
      for (int r=0;r<4;++r) mx[r] = fmaxf(mx[r], __shfl_xor(mx[r], off, 64));
    float sm[4] = {0.f,0.f,0.f,0.f};
    #pragma unroll
    for (int nt=0;nt<4;++nt)
      #pragma unroll
      for (int r=0;r<4;++r){ float e = __expf(qa[nt][r]-mx[r]); qa[nt][r]=e; sm[r]+=e; }
    #pragma unroll
    for (int off=1; off<16; off<<=1)
      #pragma unroll
      for (int r=0;r<4;++r) sm[r] += __shfl_xor(sm[r], off, 64);
    float inv[4];
    #pragma unroll
    for (int r=0;r<4;++r) inv[r] = 1.f/sm[r];
    #pragma unroll
    for (int nt=0;nt<4;++nt)
      #pragma unroll
      for (int r=0;r<4;++r){
        int row = mt*16 + lg*4 + r, col = nt*16 + l15;
        tile[row*64 + (col ^ ((row&7)<<3))] = f2bf(qa[nt][r]*inv[r]);
      }
    bf16x8 p0 = __builtin_bit_cast(bf16x8, *reinterpret_cast<const u16x8*>(tile + abase + ((     lg*8) ^ asw)));
    bf16x8 p1 = __builtin_bit_cast(bf16x8, *reinterpret_cast<const u16x8*>(tile + abase + ((32 + lg*8) ^ asw)));
    f32x4 ao[4];
    #pragma unroll
    for (int nt=0; nt<4; ++nt){
      f32x4 z = {0.f,0.f,0.f,0.f};
      z = mfma16(p0, CWF[nt*2+0], z);
      z = mfma16(p1, CWF[nt*2+1], z);
      ao[nt] = z;
    }
    float txv[4][4];
    float s1v[4] = {0.f,0.f,0.f,0.f}, s2v[4] = {0.f,0.f,0.f,0.f};
    #pragma unroll
    for (int nt=0;nt<4;++nt)
      #pragma unroll
      for (int r=0;r<4;++r){
        size_t row = (size_t)(tok0 + mt*16 + lg*4 + r);
        float v = ao[nt][r] + brv[nt] + x[row*64 + nt*16+l15];
        g_txb[row*64 + nt*16+l15] = f2bf(v);
        txv[nt][r] = v; s1v[r] += v; s2v[r] += v*v;
      }
    #pragma unroll
    for (int off=1; off<16; off<<=1)
      #pragma unroll
      for (int r=0;r<4;++r){ s1v[r] += __shfl_xor(s1v[r], off, 64); s2v[r] += __shfl_xor(s2v[r], off, 64); }
    #pragma unroll
    for (int r=0;r<4;++r){
      float mu2 = s1v[r]*(1.f/64.f);
      float rs  = rsqrtf(s2v[r]*(1.f/64.f) - mu2*mu2 + 1e-5f);
      s1v[r] = mu2; s2v[r] = rs;
    }
    #pragma unroll
    for (int nt=0;nt<4;++nt)
      #pragma unroll
      for (int r=0;r<4;++r){
        int row = mt*16 + lg*4 + r, col = nt*16 + l15;
        float n2 = (txv[nt][r]-s1v[r])*s2v[r]*g2v[nt] + be2v[nt];
        tile[row*64 + (col ^ ((row&7)<<3))] = f2bf(n2);
      }
  }

  // ---- copy n2 tile -> global (wide, coalesced; unswizzle on read) ----
  #pragma unroll
  for (int c=0;c<8;++c){
    int idx = c*64 + l;
    int tok = idx>>3, b8 = (idx&7)*8;
    u16x8 v = *reinterpret_cast<const u16x8*>(tile + tok*64 + (b8 ^ ((tok&7)<<3)));
    *reinterpret_cast<u16x8*>(n2g + (size_t)(tok0+tok)*64 + b8) = v;
  }
}

// ============ k3: W1 (on-the-fly, swapped MFMA) + conv3x3 + GELU + W2 ============
// Block = 16 x-tok x 16 y-rows. Ring rows computed in-kernel; ring is
// WAVE-PRIVATE (depthwise): wave w owns channels w*64..w*64+63. W1 output:
// swapped mfma -> lane holds 4 consecutive channels of one token -> aligned
// uint2 stores with conflict-free (p&15)<<2 XOR swizzle. n2 B-frags load
// straight from global (coalesced, prefetched 1 row ahead). 2 barriers/iter.
__global__ __launch_bounds__(256,3) void k3_conv_ffn2(
  const unsigned short* __restrict__ n2g,
  const float* __restrict__ dwp,
  const float* __restrict__ b1,
  const float* __restrict__ b2,
  const unsigned short* __restrict__ wf,
  const unsigned short* __restrict__ g_txb, float* __restrict__ out)
{
  __shared__ unsigned short ring[4][4608];   // 4 slots x 18 tok x 256 ch, 36 KB
  __shared__ unsigned short obuf[4096];      // 16 tok x 256 ch, 8 KB
  const int t = threadIdx.x, w = t>>6, l = t&63;
  const int l15 = l&15, lg = l>>4;
  const int bid = (blockIdx.x & 7)*128 + (blockIdx.x >> 3);   // XCD-chunked remap
  const int img = bid>>6;
  const int r6  = bid&63;
  const int y0  = (r6>>3)*16, xb = (r6&7)*16;

  // conv taps + bias for lane channel c = t (natural order)
  const float4 tA = *reinterpret_cast<const float4*>(&dwp[t*12]);
  const float4 tB = *reinterpret_cast<const float4*>(&dwp[t*12+4]);
  const float4 tC = *reinterpret_cast<const float4*>(&dwp[t*12+8]);  // tap8, conv bias

  // W2 frags for output quarter ntc = w
  bf16x8 W2F[8];
  #pragma unroll
  for (int q=0;q<8;++q)
    W2F[q] = ldfrag_g(wf + 32768 + (w*8 + q)*512 + l*8);
  const float4 b2q = *reinterpret_cast<const float4*>(&b2[w*16 + lg*4]);

  const unsigned short* n2img = n2g + (size_t)img*16384*64;

  // ring swizzle: off(c,p) = ((c&~3) ^ ((p&15)<<2)) | (c&3)
  const int tb4 = t & ~3, tlo = t & 3;

  // load W1 B-frags (tokens) for image row r (clamped)
  auto ldtb = [&](int r, bf16x8 tb[2][2]){
    int rc = r<0?0:(r>127?127:r);
    const unsigned short* rowp = n2img + (size_t)rc*128*64;
    #pragma unroll
    for (int tt=0;tt<2;++tt){
      int xx = xb - 8 + tt*16 + l15;
      int xc = xx<0?0:(xx>127?127:xx);
      const unsigned short* tp = rowp + xc*64;
      tb[tt][0] = ldfrag_g(tp + lg*8);
      tb[tt][1] = ldfrag_g(tp + 32 + lg*8);
    }
  };
  // W1: h row r -> ring slot sl (swapped mfma; masked SAME-pad zeros)
  auto W1row = [&](int sl, int r, bf16x8 tb[2][2]){
    const bool rv = (r >= 0 && r < 128);
    unsigned short* rg = ring[sl];
    #pragma unroll
    for (int q=0;q<4;++q){
      const int nt2 = w*4 + q;
      bf16x8 w0 = ldfrag_g(wf + 16384 + (nt2*2+0)*512 + l*8);
      bf16x8 w1 = ldfrag_g(wf + 16384 + (nt2*2+1)*512 + l*8);
      float4 b1q = *reinterpret_cast<const float4*>(&b1[nt2*16 + lg*4]);
      #pragma unroll
      for (int tt=0;tt<2;++tt){
        const int p = tt*16 + l15 - 7;      // ring position of this lane's token
        f32x4 h = {b1q.x, b1q.y, b1q.z, b1q.w};
        h = mfma16(w0, tb[tt][0], h);
        h = mfma16(w1, tb[tt][1], h);
        const int xx = xb - 1 + p;
        const bool ok = rv && xx >= 0 && xx < 128;
        float v0 = ok?h[0]:0.f, v1 = ok?h[1]:0.f, v2 = ok?h[2]:0.f, v3 = ok?h[3]:0.f;
        if (p >= 0 && p < 18){
          const int c0 = nt2*16 + lg*4;
          uint2 pk = { pack2(v0,v1), pack2(v2,v3) };
          *reinterpret_cast<uint2*>(&rg[p*256 + (c0 ^ ((p&15)<<2))]) = pk;
        }
      }
    }
  };

  // gelu: g = a / (1 + exp2(a*(C0 + C1*a^2)))
  // ---- prologue: rows y0-1, y0, y0+1 -> slots 0,1,2 (wave-private, no barrier) ----
  bf16x8 tb[2][2];
  ldtb(y0-1, tb); W1row(0, y0-1, tb);
  ldtb(y0,   tb); W1row(1, y0,   tb);
  ldtb(y0+1, tb); W1row(2, y0+1, tb);
  ldtb(y0+2, tb);

  for (int yy=0; yy<16; ++yy){
    const int gy = y0 + yy;
    // prefetch next row's n2 B-frags (T14 issue-early)
    bf16x8 tbN[2][2];
    if (yy < 15) ldtb(gy+3, tbN);
    // epilogue residual prefetch
    const size_t gtok = (size_t)img*16384 + (size_t)gy*128 + xb + l15;
    const u16x4v tq = *reinterpret_cast<const u16x4v*>(&g_txb[gtok*64 + w*16 + lg*4]);

    // W1: h row gy+2 -> ring slot (yy+3)&3
    W1row((yy+3)&3, gy+2, tb);

    // conv row gy from ring slots yy, yy+1, yy+2 (wave-private channels)
    {
      const unsigned short* rA16 = ring[(yy  )&3];
      const unsigned short* rB16 = ring[(yy+1)&3];
      const unsigned short* rC16 = ring[(yy+2)&3];
      auto swf = [&](int o) -> int { return o*256 + ((tb4 ^ ((o&15)<<2)) | tlo); };
      const int o0 = swf(0), o1 = swf(1), o2 = swf(2);
      float pA=bf2f(rA16[o0]), pB=bf2f(rB16[o0]), pC=bf2f(rC16[o0]);
      float cA=bf2f(rA16[o1]), cB=bf2f(rB16[o1]), cC=bf2f(rC16[o1]);
      unsigned short qA=rA16[o2], qB=rB16[o2], qC=rC16[o2];
      #pragma unroll
      for (int s=0;s<16;++s){
        const int oc = swf(s<15 ? s+3 : 17);
        unsigned short zA=rA16[oc], zB=rB16[oc], zC=rC16[oc];
        float nA=bf2f(qA), nB=bf2f(qB), nC=bf2f(qC);
        float a = tC.y;
        a = fmaf(tA.x,pA, a); a = fmaf(tA.y,cA, a); a = fmaf(tA.z,nA, a);
        a = fmaf(tA.w,pB, a); a = fmaf(tB.x,cB, a); a = fmaf(tB.y,nB, a);
        a = fmaf(tB.z,pC, a); a = fmaf(tB.w,cC, a); a = fmaf(tC.x,nC, a);
        float u2 = a*a;
        float arg = a*(-2.3022082f - 0.1029432f*u2);
        float e = __builtin_amdgcn_exp2f(arg);
        float g = a*__builtin_amdgcn_rcpf(1.f + e);
        obuf[s*256 + (t ^ ((s&7)<<3))] = f2bf(g);
        pA=cA; pB=cB; pC=cC; cA=nA; cB=nB; cC=nC; qA=zA; qB=zB; qC=zC;
      }
    }
    __syncthreads();   // obuf write -> cross-wave W2 read

    // W2: wave w computes output quarter w over K=256 + fused epilogue
    f32x4 oacc = {0.f,0.f,0.f,0.f};
    const int nsw = (l15&7)<<3;
    #pragma unroll
    for (int i=0;i<4;++i){
      bf16x8 fb0 = __builtin_bit_cast(bf16x8,
        *reinterpret_cast<const u16x8*>(&obuf[l15*256 + ((i*64      + lg*8) ^ nsw)]));
      bf16x8 fb1 = __builtin_bit_cast(bf16x8,
        *reinterpret_cast<const u16x8*>(&obuf[l15*256 + ((i*64 + 32 + lg*8) ^ nsw)]));
      oacc = mfma16(W2F[i*2+0], fb0, oacc);
      oacc = mfma16(W2F[i*2+1], fb1, oacc);
    }
    float4 o;
    o.x = oacc[0] + b2q.x + bf2f(tq[0]);
    o.y = oacc[1] + b2q.y + bf2f(tq[1]);
    o.z = oacc[2] + b2q.z + bf2f(tq[2]);
    o.w = oacc[3] + b2q.w + bf2f(tq[3]);
    *reinterpret_cast<float4*>(&out[gtok*64 + w*16 + lg*4]) = o;
    __syncthreads();   // W2 read done -> next iter may overwrite obuf

    if (yy < 15){
      #pragma unroll
      for (int a2=0;a2<2;++a2)
        #pragma unroll
        for (int b2i=0;b2i<2;++b2i) tb[a2][b2i] = tbN[a2][b2i];
    }
  }
}

extern "C" void kernel_launch(void* const* d_in, const int* in_sizes, int n_in,
                              void* d_out, int out_size, void* d_ws, size_t ws_size,
                              hipStream_t stream)
{
  const float* x  =(const float*)d_in[0];
  const float* g1 =(const float*)d_in[3];
  const float* be1=(const float*)d_in[4];
  const float* Wk =(const float*)d_in[5];
  const float* bk =(const float*)d_in[6];
  const float* Wq =(const float*)d_in[7];
  const float* bq =(const float*)d_in[8];
  const float* Wv =(const float*)d_in[9];
  const float* bv =(const float*)d_in[10];
  const float* Wr =(const float*)d_in[11];
  const float* br =(const float*)d_in[12];
  const float* g2 =(const float*)d_in[13];
  const float* be2=(const float*)d_in[14];
  const float* W1 =(const float*)d_in[15];
  const float* b1 =(const float*)d_in[16];
  const float* dww=(const float*)d_in[17];
  const float* dwb=(const float*)d_in[18];
  const float* W2 =(const float*)d_in[19];
  const float* b2 =(const float*)d_in[20];
  float* outp = (float*)d_out;
  char* ws = (char*)d_ws;

  unsigned short* wfb    = (unsigned short*)ws;                 // 96KB
  unsigned short* ctxWrF = (unsigned short*)(ws + 98304);       // 128KB
  float* g_sump = (float*)(ws + 229376);                        // 128KB
  float* g_part = (float*)(ws + 393216);                        // 8MB
  unsigned short* g_txb = (unsigned short*)(ws + 16777216);     // 32MB bf16
  unsigned short* n2g   = (unsigned short*)(ws + 50331648);     // 33.5MB bf16 LN2 output
  float* dwp            = (float*)(ws + 186712064);             // 12KB repacked taps+bias

  hipLaunchKernelGGL(k0_wfrag, dim3(97), dim3(64), 0, stream, Wk, Wq, Wv, Wr, W1, W2, dww, dwb, dwp, wfb);
  hipLaunchKernelGGL(k1_ctx, dim3(512), dim3(256), 0, stream, x, g1, be1, bk, bv, wfb, g_part, g_sump);
  hipLaunchKernelGGL(k15_ctxwr, dim3(16), dim3(512), 0, stream, g_part, g_sump, Wr, ctxWrF);
  hipLaunchKernelGGL(k2_attn_ffn1, dim3(1024), dim3(256), 0, stream,
                     x, g1, be1, bq, br, g2, be2, wfb, ctxWrF, g_txb, n2g);
  hipLaunchKernelGGL(k3_conv_ffn2, dim3(1024), dim3(256), 0, stream,
                     n2g, dwp, b1, b2, wfb, g_txb, outp);
}

// Round 8
// 237.444 us; speedup vs baseline: 1.4227x; 1.4227x over previous
//
#include <hip/hip_runtime.h>
#include <math.h>

typedef __bf16 bf16x8 __attribute__((ext_vector_type(8)));
typedef float f32x4 __attribute__((ext_vector_type(4)));
typedef float f32x2 __attribute__((ext_vector_type(2)));
typedef unsigned short u16x8 __attribute__((ext_vector_type(8)));
typedef unsigned short u16x4v __attribute__((ext_vector_type(4)));

constexpr int NIMG = 16384;   // H*W
constexpr int HPITCH = 130;   // padded row pitch (tokens) for g_h
constexpr int HROW = HPITCH*256; // shorts per padded image row

__device__ __forceinline__ unsigned short f2bf(float f){
  unsigned u = __builtin_bit_cast(unsigned, f);
  u += 0x7fffu + ((u>>16)&1u);
  return (unsigned short)(u>>16);
}
__device__ __forceinline__ unsigned pack2(float a, float b){
  return (unsigned)f2bf(a) | ((unsigned)f2bf(b)<<16);
}
__device__ __forceinline__ float bf2f(unsigned short h){
  unsigned u = ((unsigned)h)<<16;
  return __builtin_bit_cast(float, u);
}
__device__ __forceinline__ bf16x8 ldfrag_g(const unsigned short* p){
  u16x8 v = *reinterpret_cast<const u16x8*>(p);
  return __builtin_bit_cast(bf16x8, v);
}
__device__ __forceinline__ f32x4 mfma16(bf16x8 a, bf16x8 b, f32x4 c){
  return __builtin_amdgcn_mfma_f32_16x16x32_bf16(a, b, c, 0, 0, 0);
}

// h-channel permutation: channel c lives at slot c' = (c&15)*16 + (c>>4).
// orig(c') = ((c'&15)<<4) | (c'>>4).

// ============ k0: weights fp32 -> bf16 MFMA fragment layout (+ tap repack) ============
__global__ __launch_bounds__(64) void k0_wfrag(
  const float* __restrict__ Wk, const float* __restrict__ Wq,
  const float* __restrict__ Wv, const float* __restrict__ Wr,
  const float* __restrict__ W1, const float* __restrict__ W2,
  const float* __restrict__ dww, const float* __restrict__ dwb,
  float* __restrict__ dwp, unsigned short* __restrict__ wf)
{
  const int bid = blockIdx.x, l = threadIdx.x;
  if (bid == 96){
    // taps+bias keyed by permuted slot c': dwp[c'*12 + j] (j=0..8 taps, 9=bias)
    #pragma unroll
    for (int c=0;c<4;++c){
      int cp = l*4 + c;
      int f = ((cp&15)<<4) | (cp>>4);
      #pragma unroll
      for (int j=0;j<9;++j) dwp[cp*12 + j] = dww[f*9+j];
      dwp[cp*12 + 9]  = dwb[f];
      dwp[cp*12 + 10] = 0.f;
      dwp[cp*12 + 11] = 0.f;
    }
    return;
  }
  const float* src; int K, nt, ks; unsigned short* dst; bool perm = false;
  if (bid < 32){
    int w = bid>>3, f = bid&7;
    src = (w==0)?Wk:(w==1)?Wq:(w==2)?Wv:Wr;
    K = 64; nt = f>>1; ks = f&1;
    dst = wf + w*4096 + f*512;
  } else if (bid < 64){
    int f = bid-32; src = W1; K = 64; nt = f>>1; ks = f&1;
    dst = wf + 16384 + f*512;
  } else {
    int f = bid-64; src = W2; K = 256; nt = f>>3; ks = f&7;
    dst = wf + 32768 + f*512; perm = true;   // k index = permuted slot c'
  }
  u16x8 v;
  #pragma unroll
  for (int j=0;j<8;++j){
    int k = ks*32 + (l>>4)*8 + j;
    if (perm) k = ((k&15)<<4) | (k>>4);
    int n = nt*16 + (l&15);
    v[j] = f2bf(src[n*K + k]);
  }
  *reinterpret_cast<u16x8*>(dst + l*8) = v;
}

// ============ zhalo: zero g_h halo columns + shared zero-row ============
__global__ __launch_bounds__(256) void zhalo(unsigned* __restrict__ gh, unsigned* __restrict__ zr){
  int idx = blockIdx.x*256 + threadIdx.x;
  if (idx < 524288){
    int ch2 = idx & 127;
    int pos = idx >> 7;
    int side = pos & 1, row = pos >> 1;
    gh[(size_t)(row*HPITCH + side*(HPITCH-1))*128 + ch2] = 0;
  } else {
    int j = idx - 524288;
    if (j < HROW/2) zr[j] = 0;
  }
}

// ============ k1: LN1 + K/V proj (MFMA) + ctx accumulation (MFMA, LDS-transpose) ============
__global__ __launch_bounds__(256,2) void k1_ctx(
  const float* __restrict__ x, const float* __restrict__ g1, const float* __restrict__ be1,
  const float* __restrict__ bk, const float* __restrict__ bv,
  const unsigned short* __restrict__ wf,
  float* __restrict__ g_part, float* __restrict__ g_sump)
{
  __shared__ unsigned short tiles[4][4096];
  __shared__ float ctx_l[64*68];
  __shared__ float ssum_l[4][64];
  const int t = threadIdx.x, wid = t>>6, l = t&63;
  const int lg = l>>4, l15 = l&15;
  unsigned short* tile = tiles[wid];
  const int tok0 = blockIdx.x*512 + wid*128;

  bf16x8 WkF[8], WvF[8];
  #pragma unroll
  for (int f=0; f<8; ++f){
    WkF[f] = ldfrag_g(wf +    0 + f*512 + l*8);
    WvF[f] = ldfrag_g(wf + 8192 + f*512 + l*8);
  }
  float4 g1v  = *reinterpret_cast<const float4*>(&g1[l15*4]);
  float4 be1v = *reinterpret_cast<const float4*>(&be1[l15*4]);
  float bkv[4], bvv[4];
  #pragma unroll
  for (int ct=0; ct<4; ++ct){ bkv[ct]=bk[ct*16+l15]; bvv[ct]=bv[ct*16+l15]; }

  f32x4 acc[4][4];
  #pragma unroll
  for (int a=0;a<4;++a)
    #pragma unroll
    for (int b=0;b<4;++b) acc[a][b] = (f32x4){0.f,0.f,0.f,0.f};
  float sume[4] = {0.f,0.f,0.f,0.f};

  for (int tb=0; tb<2; ++tb){
    const int tbase = tok0 + tb*64;
    #pragma unroll
    for (int it=0; it<16; ++it){
      int row = it*4 + lg;
      float4 xv = *reinterpret_cast<const float4*>(&x[(size_t)(tbase+row)*64 + l15*4]);
      float s1 = xv.x+xv.y+xv.z+xv.w;
      float s2 = xv.x*xv.x + xv.y*xv.y + xv.z*xv.z + xv.w*xv.w;
      #pragma unroll
      for (int off=1; off<16; off<<=1){ s1 += __shfl_xor(s1,off,64); s2 += __shfl_xor(s2,off,64); }
      float mu = s1*(1.f/64.f);
      float rs = rsqrtf(s2*(1.f/64.f) - mu*mu + 1e-5f);
      uint2 pk = { pack2((xv.x-mu)*rs*g1v.x + be1v.x, (xv.y-mu)*rs*g1v.y + be1v.y),
                   pack2((xv.z-mu)*rs*g1v.z + be1v.z, (xv.w-mu)*rs*g1v.w + be1v.w) };
      *reinterpret_cast<uint2*>(&tile[row*64 + ((l15*4) ^ ((row&7)<<3))]) = pk;
    }
    bf16x8 aF[4][2];
    #pragma unroll
    for (int mt=0;mt<4;++mt){
      int row = mt*16+l15, sw=(row&7)<<3, ab=row*64;
      aF[mt][0] = __builtin_bit_cast(bf16x8, *reinterpret_cast<const u16x8*>(tile+ab+((     lg*8)^sw)));
      aF[mt][1] = __builtin_bit_cast(bf16x8, *reinterpret_cast<const u16x8*>(tile+ab+((32 + lg*8)^sw)));
    }
    #pragma unroll
    for (int half=0; half<2; ++half){
      #pragma unroll
      for (int m2=0;m2<2;++m2){
        const int mt = half*2+m2;
        #pragma unroll
        for (int ct=0;ct<4;++ct){
          f32x4 z = {0.f,0.f,0.f,0.f};
          z = mfma16(aF[mt][0], WkF[ct*2+0], z);
          z = mfma16(aF[mt][1], WkF[ct*2+1], z);
          float e0=__expf(z[0]+bkv[ct]), e1=__expf(z[1]+bkv[ct]);
          float e2=__expf(z[2]+bkv[ct]), e3=__expf(z[3]+bkv[ct]);
          sume[ct] += (e0+e1)+(e2+e3);
          const int c = ct*16+l15, sw = (c&7)<<3;
          const int cb = m2*16+lg*4;
          uint2 pe = { pack2(e0,e1), pack2(e2,e3) };
          *reinterpret_cast<uint2*>(&tile[c*64 + (cb ^ sw)]) = pe;
          f32x4 w = {0.f,0.f,0.f,0.f};
          w = mfma16(aF[mt][0], WvF[ct*2+0], w);
          w = mfma16(aF[mt][1], WvF[ct*2+1], w);
          uint2 pv = { pack2(w[0]+bvv[ct], w[1]+bvv[ct]), pack2(w[2]+bvv[ct], w[3]+bvv[ct]) };
          *reinterpret_cast<uint2*>(&tile[c*64 + ((32+cb) ^ sw)]) = pv;
        }
      }
      bf16x8 eA[4], vB[4];
      #pragma unroll
      for (int cm=0;cm<4;++cm){
        int row = cm*16+l15, sw=(row&7)<<3;
        eA[cm] = __builtin_bit_cast(bf16x8, *reinterpret_cast<const u16x8*>(tile + row*64 + ((     lg*8)^sw)));
        vB[cm] = __builtin_bit_cast(bf16x8, *reinterpret_cast<const u16x8*>(tile + row*64 + ((32 + lg*8)^sw)));
      }
      #pragma unroll
      for (int cm=0; cm<4; ++cm)
        #pragma unroll
        for (int jn=0; jn<4; ++jn)
          acc[cm][jn] = mfma16(eA[cm], vB[jn], acc[cm][jn]);
    }
  }
  #pragma unroll
  for (int ct=0; ct<4; ++ct){
    float s = sume[ct];
    s += __shfl_xor(s,16,64); s += __shfl_xor(s,32,64);
    if (lg==0) ssum_l[wid][ct*16+l15] = s;
  }
  #define CTX_RED(OP) \
    _Pragma("unroll") for (int cm=0;cm<4;++cm) \
    _Pragma("unroll") for (int jn=0;jn<4;++jn) \
    _Pragma("unroll") for (int r=0;r<4;++r) \
      ctx_l[(cm*16+lg*4+r)*68 + jn*16+l15] OP acc[cm][jn][r];
  if (wid==0){ CTX_RED(=) }  __syncthreads();
  if (wid==1){ CTX_RED(+=) } __syncthreads();
  if (wid==2){ CTX_RED(+=) } __syncthreads();
  if (wid==3){ CTX_RED(+=) } __syncthreads();
  #undef CTX_RED
  for (int i=t; i<4096; i+=256)
    g_part[(size_t)blockIdx.x*4096 + i] = ctx_l[(i>>6)*68 + (i&63)];
  if (t<64)
    g_sump[blockIdx.x*64 + t] = ssum_l[0][t]+ssum_l[1][t]+ssum_l[2][t]+ssum_l[3][t];
}

// ============ k15: reduce partials; ctxWr = (ctx_norm @ Wr^T) -> bf16 frags ============
__global__ __launch_bounds__(512) void k15_ctxwr(
  const float* __restrict__ g_part, const float* __restrict__ g_sump,
  const float* __restrict__ Wr, unsigned short* __restrict__ ctxWrF)
{
  __shared__ float sctx[4096];
  __shared__ float sWr[4096];
  __shared__ float sinv[64];
  const int b = blockIdx.x, t = threadIdx.x;
  if (t<64){
    float s=0.f;
    #pragma unroll 8
    for (int p=0;p<32;++p) s += g_sump[(b*32+p)*64 + t];
    sinv[t] = 1.f/s;
  }
  for (int idx=t; idx<4096; idx+=512){
    float s=0.f;
    #pragma unroll 8
    for (int p=0;p<32;++p) s += g_part[(size_t)(b*32+p)*4096 + idx];
    sctx[idx] = s;
  }
  __syncthreads();
  {
    int c = t>>3, d0 = (t&7)*8;
    float invc = sinv[c];
    #pragma unroll
    for (int dd=0; dd<8; ++dd){
      int d = d0+dd; float s = 0.f;
      #pragma unroll
      for (int v=0; v<64; ++v) s += sctx[c*64+v]*Wr[d*64+v];
      sWr[c*64+d] = s*invc;
    }
  }
  __syncthreads();
  {
    int f = t>>6, l = t&63, nt = f>>1, ks = f&1;
    u16x8 v;
    #pragma unroll
    for (int j=0;j<8;++j){
      int k = ks*32 + (l>>4)*8 + j;
      int n = nt*16 + (l&15);
      v[j] = f2bf(sWr[k*64+n]);
    }
    *reinterpret_cast<u16x8*>(ctxWrF + b*4096 + f*512 + l*8) = v;
  }
}

// ============ k2: LN1 + q-softmax + attn + residual + LN2 + W1 (mt-outer, wide stores) ============
__global__ __launch_bounds__(256,2) void k2_attn_ffn1(
  const float* __restrict__ x,
  const float* __restrict__ g1, const float* __restrict__ be1,
  const float* __restrict__ bq, const float* __restrict__ br,
  const float* __restrict__ g2, const float* __restrict__ be2,
  const float* __restrict__ b1,
  const unsigned short* __restrict__ wf,
  const unsigned short* __restrict__ ctxWrF,
  unsigned short* __restrict__ g_txb, unsigned short* __restrict__ g_h)
{
  __shared__ unsigned short tiles[4][4096];
  const int t = threadIdx.x, wid = t>>6, l = t&63;
  const int l15 = l&15, lg = l>>4;
  unsigned short* tile = tiles[wid];
  const int tok0 = (blockIdx.x*4 + wid)*64;
  const int img  = blockIdx.x>>6;
  const int yrow = (tok0>>7)&127;
  const int xb   = tok0&127;
  const size_t hbase = ((size_t)(img*128 + yrow)*HPITCH + 1 + xb)*256;

  bf16x8 WqF[8], CWF[8];
  #pragma unroll
  for (int f=0; f<8; ++f){
    WqF[f] = ldfrag_g(wf + 4096 + f*512 + l*8);
    CWF[f] = ldfrag_g(ctxWrF + img*4096 + f*512 + l*8);
  }
  float4 g1v  = *reinterpret_cast<const float4*>(&g1[l15*4]);
  float4 be1v = *reinterpret_cast<const float4*>(&be1[l15*4]);
  float bqv[4], brv[4], g2v[4], be2v[4];
  #pragma unroll
  for (int nt=0; nt<4; ++nt){
    bqv[nt]=bq[nt*16+l15]; brv[nt]=br[nt*16+l15];
    g2v[nt]=g2[nt*16+l15]; be2v[nt]=be2[nt*16+l15];
  }
  float b1v[16];
  #pragma unroll
  for (int i=0;i<16;++i) b1v[i]=b1[i*16+l15];

  // ---- LN1 -> swizzled bf16 tile ----
  #pragma unroll
  for (int it=0; it<16; ++it){
    int row = it*4 + lg;
    float4 xv = *reinterpret_cast<const float4*>(&x[(size_t)(tok0+row)*64 + l15*4]);
    float s1 = xv.x+xv.y+xv.z+xv.w;
    float s2 = xv.x*xv.x + xv.y*xv.y + xv.z*xv.z + xv.w*xv.w;
    #pragma unroll
    for (int off=1; off<16; off<<=1){ s1 += __shfl_xor(s1,off,64); s2 += __shfl_xor(s2,off,64); }
    float mu = s1*(1.f/64.f);
    float rs = rsqrtf(s2*(1.f/64.f) - mu*mu + 1e-5f);
    uint2 pk = { pack2((xv.x-mu)*rs*g1v.x + be1v.x, (xv.y-mu)*rs*g1v.y + be1v.y),
                 pack2((xv.z-mu)*rs*g1v.z + be1v.z, (xv.w-mu)*rs*g1v.w + be1v.w) };
    *reinterpret_cast<uint2*>(&tile[row*64 + ((l15*4) ^ ((row&7)<<3))]) = pk;
  }

  // ---- phase A: per m-tile attn chain; leaves n2 in the tile ----
  for (int mt=0; mt<4; ++mt){
    const int arow = mt*16 + l15;
    const int asw  = (arow&7)<<3;
    const int abase= arow*64;
    bf16x8 a0 = __builtin_bit_cast(bf16x8, *reinterpret_cast<const u16x8*>(tile + abase + ((     lg*8) ^ asw)));
    bf16x8 a1 = __builtin_bit_cast(bf16x8, *reinterpret_cast<const u16x8*>(tile + abase + ((32 + lg*8) ^ asw)));
    f32x4 qa[4];
    #pragma unroll
    for (int nt=0; nt<4; ++nt){
      f32x4 z = {0.f,0.f,0.f,0.f};
      z = mfma16(a0, WqF[nt*2+0], z);
      z = mfma16(a1, WqF[nt*2+1], z);
      qa[nt] = z;
    }
    #pragma unroll
    for (int nt=0; nt<4; ++nt)
      #pragma unroll
      for (int r=0; r<4; ++r) qa[nt][r] += bqv[nt];
    float mx[4];
    #pragma unroll
    for (int r=0;r<4;++r) mx[r] = fmaxf(fmaxf(qa[0][r],qa[1][r]), fmaxf(qa[2][r],qa[3][r]));
    #pragma unroll
    for (int off=1; off<16; off<<=1)
      #pragma unroll
      for (int r=0;r<4;++r) mx[r] = fmaxf(mx[r], __shfl_xor(mx[r], off, 64));
    float sm[4] = {0.f,0.f,0.f,0.f};
    #pragma unroll
    for (int nt=0;nt<4;++nt)
      #pragma unroll
      for (int r=0;r<4;++r){ float e = __expf(qa[nt][r]-mx[r]); qa[nt][r]=e; sm[r]+=e; }
    #pragma unroll
    for (int off=1; off<16; off<<=1)
      #pragma unroll
      for (int r=0;r<4;++r) sm[r] += __shfl_xor(sm[r], off, 64);
    float inv[4];
    #pragma unroll
    for (int r=0;r<4;++r) inv[r] = 1.f/sm[r];
    #pragma unroll
    for (int nt=0;nt<4;++nt)
      #pragma unroll
      for (int r=0;r<4;++r){
        int row = mt*16 + lg*4 + r, col = nt*16 + l15;
        tile[row*64 + (col ^ ((row&7)<<3))] = f2bf(qa[nt][r]*inv[r]);
      }
    bf16x8 p0 = __builtin_bit_cast(bf16x8, *reinterpret_cast<const u16x8*>(tile + abase + ((     lg*8) ^ asw)));
    bf16x8 p1 = __builtin_bit_cast(bf16x8, *reinterpret_cast<const u16x8*>(tile + abase + ((32 + lg*8) ^ asw)));
    f32x4 ao[4];
    #pragma unroll
    for (int nt=0; nt<4; ++nt){
      f32x4 z = {0.f,0.f,0.f,0.f};
      z = mfma16(p0, CWF[nt*2+0], z);
      z = mfma16(p1, CWF[nt*2+1], z);
      ao[nt] = z;
    }
    float txv[4][4];
    float s1v[4] = {0.f,0.f,0.f,0.f}, s2v[4] = {0.f,0.f,0.f,0.f};
    #pragma unroll
    for (int nt=0;nt<4;++nt)
      #pragma unroll
      for (int r=0;r<4;++r){
        size_t row = (size_t)(tok0 + mt*16 + lg*4 + r);
        float v = ao[nt][r] + brv[nt] + x[row*64 + nt*16+l15];
        g_txb[row*64 + nt*16+l15] = f2bf(v);
        txv[nt][r] = v; s1v[r] += v; s2v[r] += v*v;
      }
    #pragma unroll
    for (int off=1; off<16; off<<=1)
      #pragma unroll
      for (int r=0;r<4;++r){ s1v[r] += __shfl_xor(s1v[r], off, 64); s2v[r] += __shfl_xor(s2v[r], off, 64); }
    #pragma unroll
    for (int r=0;r<4;++r){
      float mu2 = s1v[r]*(1.f/64.f);
      float rs  = rsqrtf(s2v[r]*(1.f/64.f) - mu2*mu2 + 1e-5f);
      s1v[r] = mu2; s2v[r] = rs;
    }
    #pragma unroll
    for (int nt=0;nt<4;++nt)
      #pragma unroll
      for (int r=0;r<4;++r){
        int row = mt*16 + lg*4 + r, col = nt*16 + l15;
        float n2 = (txv[nt][r]-s1v[r])*s2v[r]*g2v[nt] + be2v[nt];
        tile[row*64 + (col ^ ((row&7)<<3))] = f2bf(n2);
      }
  }

  // ---- phase B: h = n2 @ W1^T + b1; mt-outer, register-stash, wide PERMUTED stores ----
  // channel c = nt2*16 + l15 stored at slot c' = l15*16 + nt2  => lane-contiguous rows.
  for (int mt=0; mt<4; ++mt){
    const int arow = mt*16 + l15;
    const int asw  = (arow&7)<<3;
    const int abase= arow*64;
    bf16x8 n20 = __builtin_bit_cast(bf16x8, *reinterpret_cast<const u16x8*>(tile + abase + ((     lg*8) ^ asw)));
    bf16x8 n21 = __builtin_bit_cast(bf16x8, *reinterpret_cast<const u16x8*>(tile + abase + ((32 + lg*8) ^ asw)));
    unsigned hpk[4][8];
    #pragma unroll
    for (int np=0; np<8; ++np){
      bf16x8 wa0 = ldfrag_g(wf + 16384 + (np*4+0)*512 + l*8);
      bf16x8 wa1 = ldfrag_g(wf + 16384 + (np*4+1)*512 + l*8);
      bf16x8 wb0 = ldfrag_g(wf + 16384 + (np*4+2)*512 + l*8);
      bf16x8 wb1 = ldfrag_g(wf + 16384 + (np*4+3)*512 + l*8);
      float ba = b1v[np*2], bb = b1v[np*2+1];
      f32x4 ha = {ba,ba,ba,ba};
      ha = mfma16(n20, wa0, ha);
      ha = mfma16(n21, wa1, ha);
      f32x4 hb = {bb,bb,bb,bb};
      hb = mfma16(n20, wb0, hb);
      hb = mfma16(n21, wb1, hb);
      #pragma unroll
      for (int r=0;r<4;++r) hpk[r][np] = pack2(ha[r], hb[r]);
    }
    #pragma unroll
    for (int r=0;r<4;++r){
      const size_t ro = hbase + (size_t)(mt*16+lg*4+r)*256 + l15*16;
      uint4 v0 = { hpk[r][0], hpk[r][1], hpk[r][2], hpk[r][3] };
      uint4 v1 = { hpk[r][4], hpk[r][5], hpk[r][6], hpk[r][7] };
      *reinterpret_cast<uint4*>(&g_h[ro])   = v0;
      *reinterpret_cast<uint4*>(&g_h[ro+8]) = v1;
    }
  }
}

// ============ k3: depthwise conv3x3 + GELU + W2 — rolling row window ============
// Block = 16 x-tokens x 16 y-rows, 256 thr (4 waves). 4-slot LDS row ring
// (18 tok x 256 ch bf16). Per y-iter: issue next-row loads (T14 split) ->
// conv from LDS (1 ch/lane) -> ds_write staged row -> ONE barrier -> W2 MFMA
// (wave = output quarter) -> fused epilogue. Each g_h row fetched ONCE.
__global__ __launch_bounds__(256,3) void k3_conv_ffn2(
  const unsigned short* __restrict__ g_h,
  const unsigned short* __restrict__ zrow,
  const float* __restrict__ dwp,
  const float* __restrict__ b2,
  const unsigned short* __restrict__ wf,
  const unsigned short* __restrict__ g_txb, float* __restrict__ out)
{
  __shared__ unsigned ring[4][2304];        // 4 slots x 18 tok x 512B = 36 KB
  __shared__ unsigned short obuf[2][4096];  // double-buffered 16tok x 256ch = 16 KB
  const int t = threadIdx.x, w = t>>6, l = t&63;
  const int l15 = l&15, lg = l>>4;
  const int bid = (blockIdx.x & 7)*128 + (blockIdx.x >> 3);   // XCD-chunked remap
  const int img = bid>>6;
  const int r6  = bid&63;
  const int y0  = (r6>>3)*16, x0 = (r6&7)*16;

  // taps + bias for this lane's channel c' = t (k0 pre-permuted, 12-float stride)
  const float4 tA = *reinterpret_cast<const float4*>(&dwp[t*12]);
  const float4 tB = *reinterpret_cast<const float4*>(&dwp[t*12+4]);
  const float4 tC = *reinterpret_cast<const float4*>(&dwp[t*12+8]);  // tap8, bias

  // W2 frags for output quarter ntc = w
  bf16x8 W2F[8];
  #pragma unroll
  for (int q=0;q<8;++q)
    W2F[q] = ldfrag_g(wf + 32768 + (w*8 + q)*512 + l*8);
  const float4 b2q = *reinterpret_cast<const float4*>(&b2[w*16 + lg*4]);

  const int di = w*576 + l;   // per-lane dword index into a row window (+ i*64)

  auto rowsrc = [&](int ri) -> const unsigned* {
    return (ri>=0 && ri<128)
      ? reinterpret_cast<const unsigned*>(g_h + ((size_t)(img*128+ri)*HPITCH + x0)*256)
      : reinterpret_cast<const unsigned*>(zrow + x0*256);
  };

  // prologue: stage rows y0-1, y0, y0+1 into slots 0,1,2
  {
    unsigned st[3][9];
    #pragma unroll
    for (int k=0;k<3;++k){
      const unsigned* src = rowsrc(y0-1+k);
      #pragma unroll
      for (int i=0;i<9;++i) st[k][i] = src[di + i*64];
    }
    #pragma unroll
    for (int k=0;k<3;++k)
      #pragma unroll
      for (int i=0;i<9;++i) ring[k][di + i*64] = st[k][i];
  }
  __syncthreads();

  for (int yy=0; yy<16; ++yy){
    const int gy = y0 + yy;
    // T14 issue-early: loads of row gy+2 into regs
    unsigned rr[9];
    {
      const unsigned* src = rowsrc(gy+2);
      #pragma unroll
      for (int i=0;i<9;++i) rr[i] = src[di + i*64];
    }
    // epilogue residual prefetch
    const size_t gtok = (size_t)img*16384 + (size_t)gy*128 + x0 + l15;
    const u16x4v tq = *reinterpret_cast<const u16x4v*>(&g_txb[gtok*64 + w*16 + lg*4]);

    // conv from LDS ring (rows y-1,y,y+1 = slots yy, yy+1, yy+2 mod 4)
    const unsigned short* rA16 = reinterpret_cast<const unsigned short*>(ring[(yy  )&3]);
    const unsigned short* rB16 = reinterpret_cast<const unsigned short*>(ring[(yy+1)&3]);
    const unsigned short* rC16 = reinterpret_cast<const unsigned short*>(ring[(yy+2)&3]);
    unsigned short* ob = obuf[yy&1];

    float pA=bf2f(rA16[t]),     pB=bf2f(rB16[t]),     pC=bf2f(rC16[t]);
    float cA=bf2f(rA16[256+t]), cB=bf2f(rB16[256+t]), cC=bf2f(rC16[256+t]);
    unsigned short qA=rA16[512+t], qB=rB16[512+t], qC=rC16[512+t];
    #pragma unroll
    for (int s=0;s<16;++s){
      const int o = (s<15 ? (s+3) : 17)*256 + t;   // read-ahead pos s+3
      unsigned short zA=rA16[o], zB=rB16[o], zC=rC16[o];
      float nA=bf2f(qA), nB=bf2f(qB), nC=bf2f(qC);
      float a = tC.y;
      a = fmaf(tA.x,pA, a); a = fmaf(tA.y,cA, a); a = fmaf(tA.z,nA, a);
      a = fmaf(tA.w,pB, a); a = fmaf(tB.x,cB, a); a = fmaf(tB.y,nB, a);
      a = fmaf(tB.z,pC, a); a = fmaf(tB.w,cC, a); a = fmaf(tC.x,nC, a);
      float u2 = a*a;
      float arg = a*(-2.3022082f - 0.1029432f*u2);
      float e = __builtin_amdgcn_exp2f(arg);
      float g = a*__builtin_amdgcn_rcpf(1.f + e);
      ob[s*256 + (t ^ ((s&7)<<3))] = f2bf(g);
      pA=cA; pB=cB; pC=cC; cA=nA; cB=nB; cC=nC; qA=zA; qB=zB; qC=zC;
    }

    // write-late: staged row -> slot (yy+3)&3 (compiler inserts vmcnt wait)
    {
      unsigned* dstr = ring[(yy+3)&3];
      #pragma unroll
      for (int i=0;i<9;++i) dstr[di + i*64] = rr[i];
    }
    __syncthreads();

    // W2 MFMA: wave w computes output quarter w over K=256
    f32x4 oacc = {0.f,0.f,0.f,0.f};
    const int nsw = (l15&7)<<3;
    #pragma unroll
    for (int i=0;i<4;++i){
      bf16x8 fb0 = __builtin_bit_cast(bf16x8,
        *reinterpret_cast<const u16x8*>(&ob[l15*256 + ((i*64      + lg*8) ^ nsw)]));
      bf16x8 fb1 = __builtin_bit_cast(bf16x8,
        *reinterpret_cast<const u16x8*>(&ob[l15*256 + ((i*64 + 32 + lg*8) ^ nsw)]));
      oacc = mfma16(W2F[i*2+0], fb0, oacc);
      oacc = mfma16(W2F[i*2+1], fb1, oacc);
    }
    float4 o;
    o.x = oacc[0] + b2q.x + bf2f(tq[0]);
    o.y = oacc[1] + b2q.y + bf2f(tq[1]);
    o.z = oacc[2] + b2q.z + bf2f(tq[2]);
    o.w = oacc[3] + b2q.w + bf2f(tq[3]);
    *reinterpret_cast<float4*>(&out[gtok*64 + w*16 + lg*4]) = o;
  }
}

extern "C" void kernel_launch(void* const* d_in, const int* in_sizes, int n_in,
                              void* d_out, int out_size, void* d_ws, size_t ws_size,
                              hipStream_t stream)
{
  const float* x  =(const float*)d_in[0];
  const float* g1 =(const float*)d_in[3];
  const float* be1=(const float*)d_in[4];
  const float* Wk =(const float*)d_in[5];
  const float* bk =(const float*)d_in[6];
  const float* Wq =(const float*)d_in[7];
  const float* bq =(const float*)d_in[8];
  const float* Wv =(const float*)d_in[9];
  const float* bv =(const float*)d_in[10];
  const float* Wr =(const float*)d_in[11];
  const float* br =(const float*)d_in[12];
  const float* g2 =(const float*)d_in[13];
  const float* be2=(const float*)d_in[14];
  const float* W1 =(const float*)d_in[15];
  const float* b1 =(const float*)d_in[16];
  const float* dww=(const float*)d_in[17];
  const float* dwb=(const float*)d_in[18];
  const float* W2 =(const float*)d_in[19];
  const float* b2 =(const float*)d_in[20];
  float* outp = (float*)d_out;
  char* ws = (char*)d_ws;

  unsigned short* wfb    = (unsigned short*)ws;                 // 96KB
  unsigned short* ctxWrF = (unsigned short*)(ws + 98304);       // 128KB
  float* g_sump = (float*)(ws + 229376);                        // 128KB
  float* g_part = (float*)(ws + 393216);                        // 8MB
  unsigned short* g_txb = (unsigned short*)(ws + 16777216);     // 32MB bf16
  unsigned short* g_h   = (unsigned short*)(ws + 50331648);     // 136.3MB padded bf16
  unsigned short* zr    = (unsigned short*)(ws + 186646528);    // 65KB zero row
  float* dwp            = (float*)(ws + 186712064);             // 12KB repacked taps+bias

  hipLaunchKernelGGL(k0_wfrag, dim3(97), dim3(64), 0, stream, Wk, Wq, Wv, Wr, W1, W2, dww, dwb, dwp, wfb);
  hipLaunchKernelGGL(zhalo, dim3(2113), dim3(256), 0, stream, (unsigned*)g_h, (unsigned*)zr);
  hipLaunchKernelGGL(k1_ctx, dim3(512), dim3(256), 0, stream, x, g1, be1, bk, bv, wfb, g_part, g_sump);
  hipLaunchKernelGGL(k15_ctxwr, dim3(16), dim3(512), 0, stream, g_part, g_sump, Wr, ctxWrF);
  hipLaunchKernelGGL(k2_attn_ffn1, dim3(1024), dim3(256), 0, stream,
                     x, g1, be1, bq, br, g2, be2, b1, wfb, ctxWrF, g_txb, g_h);
  hipLaunchKernelGGL(k3_conv_ffn2, dim3(1024), dim3(256), 0, stream,
                     g_h, zr, dwp, b2, wfb, g_txb, outp);
}

// Round 9
// 209.948 us; speedup vs baseline: 1.6090x; 1.1310x over previous
//
#include <hip/hip_runtime.h>
#include <math.h>

typedef __bf16 bf16x8 __attribute__((ext_vector_type(8)));
typedef float f32x4 __attribute__((ext_vector_type(4)));
typedef float f32x2 __attribute__((ext_vector_type(2)));
typedef unsigned short u16x8 __attribute__((ext_vector_type(8)));
typedef unsigned short u16x4v __attribute__((ext_vector_type(4)));

constexpr int NIMG = 16384;   // H*W
constexpr int HPITCH = 130;   // padded row pitch (tokens) for g_h

__device__ __forceinline__ unsigned short f2bf(float f){
  unsigned u = __builtin_bit_cast(unsigned, f);
  u += 0x7fffu + ((u>>16)&1u);
  return (unsigned short)(u>>16);
}
__device__ __forceinline__ unsigned pack2(float a, float b){
  return (unsigned)f2bf(a) | ((unsigned)f2bf(b)<<16);
}
__device__ __forceinline__ float bf2f(unsigned short h){
  unsigned u = ((unsigned)h)<<16;
  return __builtin_bit_cast(float, u);
}
__device__ __forceinline__ bf16x8 ldfrag_g(const unsigned short* p){
  u16x8 v = *reinterpret_cast<const u16x8*>(p);
  return __builtin_bit_cast(bf16x8, v);
}
__device__ __forceinline__ f32x4 mfma16(bf16x8 a, bf16x8 b, f32x4 c){
  return __builtin_amdgcn_mfma_f32_16x16x32_bf16(a, b, c, 0, 0, 0);
}

// h-channel permutation: channel c lives at slot c' = (c&15)*16 + (c>>4).
// orig(c') = ((c'&15)<<4) | (c'>>4).  g_h stores fp8-e4m3 (1 B/ch).

// ============ k0: weights fp32 -> bf16 MFMA fragment layout (+ tap repack) ============
__global__ __launch_bounds__(64) void k0_wfrag(
  const float* __restrict__ Wk, const float* __restrict__ Wq,
  const float* __restrict__ Wv, const float* __restrict__ Wr,
  const float* __restrict__ W1, const float* __restrict__ W2,
  const float* __restrict__ dww, const float* __restrict__ dwb,
  float* __restrict__ dwp, unsigned short* __restrict__ wf)
{
  const int bid = blockIdx.x, l = threadIdx.x;
  if (bid == 96){
    // taps+bias keyed by permuted slot c': dwp[c'*12 + j] (j=0..8 taps, 9=bias)
    #pragma unroll
    for (int c=0;c<4;++c){
      int cp = l*4 + c;
      int f = ((cp&15)<<4) | (cp>>4);
      #pragma unroll
      for (int j=0;j<9;++j) dwp[cp*12 + j] = dww[f*9+j];
      dwp[cp*12 + 9]  = dwb[f];
      dwp[cp*12 + 10] = 0.f;
      dwp[cp*12 + 11] = 0.f;
    }
    return;
  }
  const float* src; int K, nt, ks; unsigned short* dst; bool perm = false;
  if (bid < 32){
    int w = bid>>3, f = bid&7;
    src = (w==0)?Wk:(w==1)?Wq:(w==2)?Wv:Wr;
    K = 64; nt = f>>1; ks = f&1;
    dst = wf + w*4096 + f*512;
  } else if (bid < 64){
    int f = bid-32; src = W1; K = 64; nt = f>>1; ks = f&1;
    dst = wf + 16384 + f*512;
  } else {
    int f = bid-64; src = W2; K = 256; nt = f>>3; ks = f&7;
    dst = wf + 32768 + f*512; perm = true;   // k index = permuted slot c'
  }
  u16x8 v;
  #pragma unroll
  for (int j=0;j<8;++j){
    int k = ks*32 + (l>>4)*8 + j;
    if (perm) k = ((k&15)<<4) | (k>>4);
    int n = nt*16 + (l&15);
    v[j] = f2bf(src[n*K + k]);
  }
  *reinterpret_cast<u16x8*>(dst + l*8) = v;
}

// ============ zhalo: zero g_h halo columns (fp8) + shared zero-row ============
__global__ __launch_bounds__(256) void zhalo(unsigned* __restrict__ gh, unsigned* __restrict__ zr){
  int idx = blockIdx.x*256 + threadIdx.x;
  if (idx < 262144){
    int ch = idx & 63;           // dword within token (64 dwords = 256 fp8)
    int pos = idx >> 6;
    int side = pos & 1, row = pos >> 1;
    gh[(size_t)(row*HPITCH + side*(HPITCH-1))*64 + ch] = 0;
  } else {
    int j = idx - 262144;
    if (j < 8320) zr[j] = 0;     // 130 tok x 256 fp8 = 8320 dwords
  }
}

// ============ k1: LN1 + K/V proj (MFMA) + ctx accumulation (MFMA, LDS-transpose) ============
__global__ __launch_bounds__(256,2) void k1_ctx(
  const float* __restrict__ x, const float* __restrict__ g1, const float* __restrict__ be1,
  const float* __restrict__ bk, const float* __restrict__ bv,
  const unsigned short* __restrict__ wf,
  float* __restrict__ g_part, float* __restrict__ g_sump)
{
  __shared__ unsigned short tiles[4][4096];
  __shared__ float ctx_l[64*68];
  __shared__ float ssum_l[4][64];
  const int t = threadIdx.x, wid = t>>6, l = t&63;
  const int lg = l>>4, l15 = l&15;
  unsigned short* tile = tiles[wid];
  const int tok0 = blockIdx.x*512 + wid*128;

  bf16x8 WkF[8], WvF[8];
  #pragma unroll
  for (int f=0; f<8; ++f){
    WkF[f] = ldfrag_g(wf +    0 + f*512 + l*8);
    WvF[f] = ldfrag_g(wf + 8192 + f*512 + l*8);
  }
  float4 g1v  = *reinterpret_cast<const float4*>(&g1[l15*4]);
  float4 be1v = *reinterpret_cast<const float4*>(&be1[l15*4]);
  float bkv[4], bvv[4];
  #pragma unroll
  for (int ct=0; ct<4; ++ct){ bkv[ct]=bk[ct*16+l15]; bvv[ct]=bv[ct*16+l15]; }

  f32x4 acc[4][4];
  #pragma unroll
  for (int a=0;a<4;++a)
    #pragma unroll
    for (int b=0;b<4;++b) acc[a][b] = (f32x4){0.f,0.f,0.f,0.f};
  float sume[4] = {0.f,0.f,0.f,0.f};

  for (int tb=0; tb<2; ++tb){
    const int tbase = tok0 + tb*64;
    #pragma unroll
    for (int it=0; it<16; ++it){
      int row = it*4 + lg;
      float4 xv = *reinterpret_cast<const float4*>(&x[(size_t)(tbase+row)*64 + l15*4]);
      float s1 = xv.x+xv.y+xv.z+xv.w;
      float s2 = xv.x*xv.x + xv.y*xv.y + xv.z*xv.z + xv.w*xv.w;
      #pragma unroll
      for (int off=1; off<16; off<<=1){ s1 += __shfl_xor(s1,off,64); s2 += __shfl_xor(s2,off,64); }
      float mu = s1*(1.f/64.f);
      float rs = rsqrtf(s2*(1.f/64.f) - mu*mu + 1e-5f);
      uint2 pk = { pack2((xv.x-mu)*rs*g1v.x + be1v.x, (xv.y-mu)*rs*g1v.y + be1v.y),
                   pack2((xv.z-mu)*rs*g1v.z + be1v.z, (xv.w-mu)*rs*g1v.w + be1v.w) };
      *reinterpret_cast<uint2*>(&tile[row*64 + ((l15*4) ^ ((row&7)<<3))]) = pk;
    }
    bf16x8 aF[4][2];
    #pragma unroll
    for (int mt=0;mt<4;++mt){
      int row = mt*16+l15, sw=(row&7)<<3, ab=row*64;
      aF[mt][0] = __builtin_bit_cast(bf16x8, *reinterpret_cast<const u16x8*>(tile+ab+((     lg*8)^sw)));
      aF[mt][1] = __builtin_bit_cast(bf16x8, *reinterpret_cast<const u16x8*>(tile+ab+((32 + lg*8)^sw)));
    }
    #pragma unroll
    for (int half=0; half<2; ++half){
      #pragma unroll
      for (int m2=0;m2<2;++m2){
        const int mt = half*2+m2;
        #pragma unroll
        for (int ct=0;ct<4;++ct){
          f32x4 z = {0.f,0.f,0.f,0.f};
          z = mfma16(aF[mt][0], WkF[ct*2+0], z);
          z = mfma16(aF[mt][1], WkF[ct*2+1], z);
          float e0=__expf(z[0]+bkv[ct]), e1=__expf(z[1]+bkv[ct]);
          float e2=__expf(z[2]+bkv[ct]), e3=__expf(z[3]+bkv[ct]);
          sume[ct] += (e0+e1)+(e2+e3);
          const int c = ct*16+l15, sw = (c&7)<<3;
          const int cb = m2*16+lg*4;
          uint2 pe = { pack2(e0,e1), pack2(e2,e3) };
          *reinterpret_cast<uint2*>(&tile[c*64 + (cb ^ sw)]) = pe;
          f32x4 w = {0.f,0.f,0.f,0.f};
          w = mfma16(aF[mt][0], WvF[ct*2+0], w);
          w = mfma16(aF[mt][1], WvF[ct*2+1], w);
          uint2 pv = { pack2(w[0]+bvv[ct], w[1]+bvv[ct]), pack2(w[2]+bvv[ct], w[3]+bvv[ct]) };
          *reinterpret_cast<uint2*>(&tile[c*64 + ((32+cb) ^ sw)]) = pv;
        }
      }
      bf16x8 eA[4], vB[4];
      #pragma unroll
      for (int cm=0;cm<4;++cm){
        int row = cm*16+l15, sw=(row&7)<<3;
        eA[cm] = __builtin_bit_cast(bf16x8, *reinterpret_cast<const u16x8*>(tile + row*64 + ((     lg*8)^sw)));
        vB[cm] = __builtin_bit_cast(bf16x8, *reinterpret_cast<const u16x8*>(tile + row*64 + ((32 + lg*8)^sw)));
      }
      #pragma unroll
      for (int cm=0; cm<4; ++cm)
        #pragma unroll
        for (int jn=0; jn<4; ++jn)
          acc[cm][jn] = mfma16(eA[cm], vB[jn], acc[cm][jn]);
    }
  }
  #pragma unroll
  for (int ct=0; ct<4; ++ct){
    float s = sume[ct];
    s += __shfl_xor(s,16,64); s += __shfl_xor(s,32,64);
    if (lg==0) ssum_l[wid][ct*16+l15] = s;
  }
  #define CTX_RED(OP) \
    _Pragma("unroll") for (int cm=0;cm<4;++cm) \
    _Pragma("unroll") for (int jn=0;jn<4;++jn) \
    _Pragma("unroll") for (int r=0;r<4;++r) \
      ctx_l[(cm*16+lg*4+r)*68 + jn*16+l15] OP acc[cm][jn][r];
  if (wid==0){ CTX_RED(=) }  __syncthreads();
  if (wid==1){ CTX_RED(+=) } __syncthreads();
  if (wid==2){ CTX_RED(+=) } __syncthreads();
  if (wid==3){ CTX_RED(+=) } __syncthreads();
  #undef CTX_RED
  for (int i=t; i<4096; i+=256)
    g_part[(size_t)blockIdx.x*4096 + i] = ctx_l[(i>>6)*68 + (i&63)];
  if (t<64)
    g_sump[blockIdx.x*64 + t] = ssum_l[0][t]+ssum_l[1][t]+ssum_l[2][t]+ssum_l[3][t];
}

// ============ k15: reduce partials; ctxWr = (ctx_norm @ Wr^T) -> bf16 frags ============
__global__ __launch_bounds__(512) void k15_ctxwr(
  const float* __restrict__ g_part, const float* __restrict__ g_sump,
  const float* __restrict__ Wr, unsigned short* __restrict__ ctxWrF)
{
  __shared__ float sctx[4096];
  __shared__ float sWr[4096];
  __shared__ float sinv[64];
  const int b = blockIdx.x, t = threadIdx.x;
  if (t<64){
    float s=0.f;
    #pragma unroll 8
    for (int p=0;p<32;++p) s += g_sump[(b*32+p)*64 + t];
    sinv[t] = 1.f/s;
  }
  for (int idx=t; idx<4096; idx+=512){
    float s=0.f;
    #pragma unroll 8
    for (int p=0;p<32;++p) s += g_part[(size_t)(b*32+p)*4096 + idx];
    sctx[idx] = s;
  }
  __syncthreads();
  {
    int c = t>>3, d0 = (t&7)*8;
    float invc = sinv[c];
    #pragma unroll
    for (int dd=0; dd<8; ++dd){
      int d = d0+dd; float s = 0.f;
      #pragma unroll
      for (int v=0; v<64; ++v) s += sctx[c*64+v]*Wr[d*64+v];
      sWr[c*64+d] = s*invc;
    }
  }
  __syncthreads();
  {
    int f = t>>6, l = t&63, nt = f>>1, ks = f&1;
    u16x8 v;
    #pragma unroll
    for (int j=0;j<8;++j){
      int k = ks*32 + (l>>4)*8 + j;
      int n = nt*16 + (l&15);
      v[j] = f2bf(sWr[k*64+n]);
    }
    *reinterpret_cast<u16x8*>(ctxWrF + b*4096 + f*512 + l*8) = v;
  }
}

// ============ k2: LN1 + q-softmax + attn + residual + LN2 + W1 -> fp8 g_h ============
__global__ __launch_bounds__(256,2) void k2_attn_ffn1(
  const float* __restrict__ x,
  const float* __restrict__ g1, const float* __restrict__ be1,
  const float* __restrict__ bq, const float* __restrict__ br,
  const float* __restrict__ g2, const float* __restrict__ be2,
  const float* __restrict__ b1,
  const unsigned short* __restrict__ wf,
  const unsigned short* __restrict__ ctxWrF,
  unsigned short* __restrict__ g_txb, unsigned char* __restrict__ g_h)
{
  __shared__ unsigned short tiles[4][4096];
  const int t = threadIdx.x, wid = t>>6, l = t&63;
  const int l15 = l&15, lg = l>>4;
  unsigned short* tile = tiles[wid];
  const int tok0 = (blockIdx.x*4 + wid)*64;
  const int img  = blockIdx.x>>6;
  const int yrow = (tok0>>7)&127;
  const int xb   = tok0&127;
  const size_t hbase = ((size_t)(img*128 + yrow)*HPITCH + 1 + xb)*256;  // BYTES (fp8)

  bf16x8 WqF[8], CWF[8];
  #pragma unroll
  for (int f=0; f<8; ++f){
    WqF[f] = ldfrag_g(wf + 4096 + f*512 + l*8);
    CWF[f] = ldfrag_g(ctxWrF + img*4096 + f*512 + l*8);
  }
  float4 g1v  = *reinterpret_cast<const float4*>(&g1[l15*4]);
  float4 be1v = *reinterpret_cast<const float4*>(&be1[l15*4]);
  float bqv[4], brv[4], g2v[4], be2v[4];
  #pragma unroll
  for (int nt=0; nt<4; ++nt){
    bqv[nt]=bq[nt*16+l15]; brv[nt]=br[nt*16+l15];
    g2v[nt]=g2[nt*16+l15]; be2v[nt]=be2[nt*16+l15];
  }
  float b1v[16];
  #pragma unroll
  for (int i=0;i<16;++i) b1v[i]=b1[i*16+l15];

  // ---- LN1 -> swizzled bf16 tile ----
  #pragma unroll
  for (int it=0; it<16; ++it){
    int row = it*4 + lg;
    float4 xv = *reinterpret_cast<const float4*>(&x[(size_t)(tok0+row)*64 + l15*4]);
    float s1 = xv.x+xv.y+xv.z+xv.w;
    float s2 = xv.x*xv.x + xv.y*xv.y + xv.z*xv.z + xv.w*xv.w;
    #pragma unroll
    for (int off=1; off<16; off<<=1){ s1 += __shfl_xor(s1,off,64); s2 += __shfl_xor(s2,off,64); }
    float mu = s1*(1.f/64.f);
    float rs = rsqrtf(s2*(1.f/64.f) - mu*mu + 1e-5f);
    uint2 pk = { pack2((xv.x-mu)*rs*g1v.x + be1v.x, (xv.y-mu)*rs*g1v.y + be1v.y),
                 pack2((xv.z-mu)*rs*g1v.z + be1v.z, (xv.w-mu)*rs*g1v.w + be1v.w) };
    *reinterpret_cast<uint2*>(&tile[row*64 + ((l15*4) ^ ((row&7)<<3))]) = pk;
  }

  // ---- phase A: per m-tile attn chain; leaves n2 in the tile ----
  for (int mt=0; mt<4; ++mt){
    const int arow = mt*16 + l15;
    const int asw  = (arow&7)<<3;
    const int abase= arow*64;
    bf16x8 a0 = __builtin_bit_cast(bf16x8, *reinterpret_cast<const u16x8*>(tile + abase + ((     lg*8) ^ asw)));
    bf16x8 a1 = __builtin_bit_cast(bf16x8, *reinterpret_cast<const u16x8*>(tile + abase + ((32 + lg*8) ^ asw)));
    f32x4 qa[4];
    #pragma unroll
    for (int nt=0; nt<4; ++nt){
      f32x4 z = {0.f,0.f,0.f,0.f};
      z = mfma16(a0, WqF[nt*2+0], z);
      z = mfma16(a1, WqF[nt*2+1], z);
      qa[nt] = z;
    }
    #pragma unroll
    for (int nt=0; nt<4; ++nt)
      #pragma unroll
      for (int r=0; r<4; ++r) qa[nt][r] += bqv[nt];
    float mx[4];
    #pragma unroll
    for (int r=0;r<4;++r) mx[r] = fmaxf(fmaxf(qa[0][r],qa[1][r]), fmaxf(qa[2][r],qa[3][r]));
    #pragma unroll
    for (int off=1; off<16; off<<=1)
      #pragma unroll
      for (int r=0;r<4;++r) mx[r] = fmaxf(mx[r], __shfl_xor(mx[r], off, 64));
    float sm[4] = {0.f,0.f,0.f,0.f};
    #pragma unroll
    for (int nt=0;nt<4;++nt)
      #pragma unroll
      for (int r=0;r<4;++r){ float e = __expf(qa[nt][r]-mx[r]); qa[nt][r]=e; sm[r]+=e; }
    #pragma unroll
    for (int off=1; off<16; off<<=1)
      #pragma unroll
      for (int r=0;r<4;++r) sm[r] += __shfl_xor(sm[r], off, 64);
    float inv[4];
    #pragma unroll
    for (int r=0;r<4;++r) inv[r] = 1.f/sm[r];
    #pragma unroll
    for (int nt=0;nt<4;++nt)
      #pragma unroll
      for (int r=0;r<4;++r){
        int row = mt*16 + lg*4 + r, col = nt*16 + l15;
        tile[row*64 + (col ^ ((row&7)<<3))] = f2bf(qa[nt][r]*inv[r]);
      }
    bf16x8 p0 = __builtin_bit_cast(bf16x8, *reinterpret_cast<const u16x8*>(tile + abase + ((     lg*8) ^ asw)));
    bf16x8 p1 = __builtin_bit_cast(bf16x8, *reinterpret_cast<const u16x8*>(tile + abase + ((32 + lg*8) ^ asw)));
    f32x4 ao[4];
    #pragma unroll
    for (int nt=0; nt<4; ++nt){
      f32x4 z = {0.f,0.f,0.f,0.f};
      z = mfma16(p0, CWF[nt*2+0], z);
      z = mfma16(p1, CWF[nt*2+1], z);
      ao[nt] = z;
    }
    float txv[4][4];
    float s1v[4] = {0.f,0.f,0.f,0.f}, s2v[4] = {0.f,0.f,0.f,0.f};
    #pragma unroll
    for (int nt=0;nt<4;++nt)
      #pragma unroll
      for (int r=0;r<4;++r){
        size_t row = (size_t)(tok0 + mt*16 + lg*4 + r);
        float v = ao[nt][r] + brv[nt] + x[row*64 + nt*16+l15];
        g_txb[row*64 + nt*16+l15] = f2bf(v);
        txv[nt][r] = v; s1v[r] += v; s2v[r] += v*v;
      }
    #pragma unroll
    for (int off=1; off<16; off<<=1)
      #pragma unroll
      for (int r=0;r<4;++r){ s1v[r] += __shfl_xor(s1v[r], off, 64); s2v[r] += __shfl_xor(s2v[r], off, 64); }
    #pragma unroll
    for (int r=0;r<4;++r){
      float mu2 = s1v[r]*(1.f/64.f);
      float rs  = rsqrtf(s2v[r]*(1.f/64.f) - mu2*mu2 + 1e-5f);
      s1v[r] = mu2; s2v[r] = rs;
    }
    #pragma unroll
    for (int nt=0;nt<4;++nt)
      #pragma unroll
      for (int r=0;r<4;++r){
        int row = mt*16 + lg*4 + r, col = nt*16 + l15;
        float n2 = (txv[nt][r]-s1v[r])*s2v[r]*g2v[nt] + be2v[nt];
        tile[row*64 + (col ^ ((row&7)<<3))] = f2bf(n2);
      }
  }

  // ---- phase B: h = n2 @ W1^T + b1; mt-outer, fp8-packed PERMUTED uint4 stores ----
  // channel c = nt2*16 + l15 stored at slot c' = l15*16 + nt2  => 16 contiguous fp8/thread/row.
  for (int mt=0; mt<4; ++mt){
    const int arow = mt*16 + l15;
    const int asw  = (arow&7)<<3;
    const int abase= arow*64;
    bf16x8 n20 = __builtin_bit_cast(bf16x8, *reinterpret_cast<const u16x8*>(tile + abase + ((     lg*8) ^ asw)));
    bf16x8 n21 = __builtin_bit_cast(bf16x8, *reinterpret_cast<const u16x8*>(tile + abase + ((32 + lg*8) ^ asw)));
    unsigned hq[4][4];
    #pragma unroll
    for (int np=0; np<8; ++np){
      bf16x8 wa0 = ldfrag_g(wf + 16384 + (np*4+0)*512 + l*8);
      bf16x8 wa1 = ldfrag_g(wf + 16384 + (np*4+1)*512 + l*8);
      bf16x8 wb0 = ldfrag_g(wf + 16384 + (np*4+2)*512 + l*8);
      bf16x8 wb1 = ldfrag_g(wf + 16384 + (np*4+3)*512 + l*8);
      float ba = b1v[np*2], bb = b1v[np*2+1];
      f32x4 ha = {ba,ba,ba,ba};
      ha = mfma16(n20, wa0, ha);
      ha = mfma16(n21, wa1, ha);
      f32x4 hb = {bb,bb,bb,bb};
      hb = mfma16(n20, wb0, hb);
      hb = mfma16(n21, wb1, hb);
      const int d = np>>1;
      if ((np&1)==0){
        #pragma unroll
        for (int r=0;r<4;++r)
          hq[r][d] = (unsigned)__builtin_amdgcn_cvt_pk_fp8_f32(ha[r], hb[r], 0, false);
      } else {
        #pragma unroll
        for (int r=0;r<4;++r)
          hq[r][d] = (unsigned)__builtin_amdgcn_cvt_pk_fp8_f32(ha[r], hb[r], (int)hq[r][d], true);
      }
    }
    #pragma unroll
    for (int r=0;r<4;++r){
      const size_t ro = hbase + (size_t)(mt*16+lg*4+r)*256 + l15*16;
      uint4 v = { hq[r][0], hq[r][1], hq[r][2], hq[r][3] };
      *reinterpret_cast<uint4*>(g_h + ro) = v;
    }
  }
}

// ============ k3: depthwise conv3x3 + GELU + W2 — rolling row window (fp8 g_h) ============
// Block = 16 x-tokens x 16 y-rows, 256 thr. 4-slot LDS bf16 row ring, 129-dword
// pitch. Per y-iter: issue next-row fp8 loads (T14 split) -> conv from LDS ->
// fp8->bf16 convert + ds_write staged row -> ONE barrier -> W2 MFMA -> epilogue.
__global__ __launch_bounds__(256,3) void k3_conv_ffn2(
  const unsigned char* __restrict__ g_h,
  const unsigned char* __restrict__ zrow,
  const float* __restrict__ dwp,
  const float* __restrict__ b2,
  const unsigned short* __restrict__ wf,
  const unsigned short* __restrict__ g_txb, float* __restrict__ out)
{
  __shared__ unsigned ring[4][2322];        // 4 slots x 18 tok x 129-dword pitch = 37.2 KB
  __shared__ unsigned short obuf[2][4096];  // double-buffered 16tok x 256ch = 16 KB
  const int t = threadIdx.x, w = t>>6, l = t&63;
  const int l15 = l&15, lg = l>>4;
  const int bid = (blockIdx.x & 7)*128 + (blockIdx.x >> 3);   // XCD-chunked remap
  const int img = bid>>6;
  const int r6  = bid&63;
  const int y0  = (r6>>3)*16, x0 = (r6&7)*16;

  // taps + bias for this lane's channel c' = t (k0 pre-permuted, 12-float stride)
  const float4 tA = *reinterpret_cast<const float4*>(&dwp[t*12]);
  const float4 tB = *reinterpret_cast<const float4*>(&dwp[t*12+4]);
  const float4 tC = *reinterpret_cast<const float4*>(&dwp[t*12+8]);  // tap8, bias

  // W2 frags for output quarter ntc = w
  bf16x8 W2F[8];
  #pragma unroll
  for (int q=0;q<8;++q)
    W2F[q] = ldfrag_g(wf + 32768 + (w*8 + q)*512 + l*8);
  const float4 b2q = *reinterpret_cast<const float4*>(&b2[w*16 + lg*4]);

  // staging map: thread t stages token pos pi = 1 + (t&15), channels c0..c0+15
  // (global uint4 coalesced in 64B groups; LDS writes conflict-free: banks m+8g)
  const int pi = 1 + (t&15);
  const int c0 = (t>>4)*16;

  auto rowsrc = [&](int ri) -> const unsigned char* {
    return (ri>=0 && ri<128)
      ? g_h + ((size_t)(img*128+ri)*HPITCH + x0)*256
      : zrow + x0*256;
  };
  auto ldrow = [&](int ri, uint4* m, unsigned* h){
    const unsigned char* src = rowsrc(ri);
    *m = *reinterpret_cast<const uint4*>(src + pi*256 + c0);
    if (t < 128){
      int ph = (t<64)?0:17, dh = t&63;
      *h = reinterpret_cast<const unsigned*>(src + ph*256)[dh];
    }
  };
  auto cvtwr = [&](unsigned* rg, int base, unsigned mdw){
    f32x2 lo = __builtin_amdgcn_cvt_pk_f32_fp8((int)mdw, false);
    f32x2 hi = __builtin_amdgcn_cvt_pk_f32_fp8((int)mdw, true);
    unsigned plo, phi;
    asm("v_cvt_pk_bf16_f32 %0, %1, %2" : "=v"(plo) : "v"(lo[0]), "v"(lo[1]));
    asm("v_cvt_pk_bf16_f32 %0, %1, %2" : "=v"(phi) : "v"(hi[0]), "v"(hi[1]));
    rg[base]   = plo;
    rg[base+1] = phi;
  };
  auto wrrow = [&](int sl, uint4 m, unsigned h){
    unsigned* rg = ring[sl];
    const int base = pi*129 + (c0>>1);
    #pragma unroll
    for (int d=0; d<4; ++d) cvtwr(rg, base + 2*d, m[d]);
    if (t < 128){
      int ph = (t<64)?0:17, dh = t&63;
      cvtwr(rg, ph*129 + 2*dh, h);
    }
  };

  // prologue: stage rows y0-1, y0, y0+1 into slots 0,1,2
  {
    uint4 m0,m1,m2; unsigned h0=0,h1=0,h2=0;
    ldrow(y0-1,&m0,&h0); ldrow(y0,&m1,&h1); ldrow(y0+1,&m2,&h2);
    wrrow(0,m0,h0); wrrow(1,m1,h1); wrrow(2,m2,h2);
  }
  __syncthreads();

  for (int yy=0; yy<16; ++yy){
    const int gy = y0 + yy;
    // T14 issue-early: fp8 loads of row gy+2 into regs
    uint4 rm; unsigned rh = 0;
    ldrow(gy+2, &rm, &rh);
    // epilogue residual prefetch
    const size_t gtok = (size_t)img*16384 + (size_t)gy*128 + x0 + l15;
    const u16x4v tq = *reinterpret_cast<const u16x4v*>(&g_txb[gtok*64 + w*16 + lg*4]);

    // conv from LDS ring (rows y-1,y,y+1 = slots yy, yy+1, yy+2 mod 4); u16 pitch 258
    const unsigned short* rA16 = reinterpret_cast<const unsigned short*>(ring[(yy  )&3]);
    const unsigned short* rB16 = reinterpret_cast<const unsigned short*>(ring[(yy+1)&3]);
    const unsigned short* rC16 = reinterpret_cast<const unsigned short*>(ring[(yy+2)&3]);
    unsigned short* ob = obuf[yy&1];

    float pA=bf2f(rA16[t]),     pB=bf2f(rB16[t]),     pC=bf2f(rC16[t]);
    float cA=bf2f(rA16[258+t]), cB=bf2f(rB16[258+t]), cC=bf2f(rC16[258+t]);
    unsigned short qA=rA16[516+t], qB=rB16[516+t], qC=rC16[516+t];
    #pragma unroll
    for (int s=0;s<16;++s){
      const int o = (s<15 ? (s+3) : 17)*258 + t;   // read-ahead pos s+3
      unsigned short zA=rA16[o], zB=rB16[o], zC=rC16[o];
      float nA=bf2f(qA), nB=bf2f(qB), nC=bf2f(qC);
      float a = tC.y;
      a = fmaf(tA.x,pA, a); a = fmaf(tA.y,cA, a); a = fmaf(tA.z,nA, a);
      a = fmaf(tA.w,pB, a); a = fmaf(tB.x,cB, a); a = fmaf(tB.y,nB, a);
      a = fmaf(tB.z,pC, a); a = fmaf(tB.w,cC, a); a = fmaf(tC.x,nC, a);
      float u2 = a*a;
      float arg = a*(-2.3022082f - 0.1029432f*u2);
      float e = __builtin_amdgcn_exp2f(arg);
      float g = a*__builtin_amdgcn_rcpf(1.f + e);
      ob[s*256 + (t ^ ((s&7)<<3))] = f2bf(g);
      pA=cA; pB=cB; pC=cC; cA=nA; cB=nB; cC=nC; qA=zA; qB=zB; qC=zC;
    }

    // write-late: convert staged fp8 row -> bf16 ring slot (yy+3)&3
    wrrow((yy+3)&3, rm, rh);
    __syncthreads();

    // W2 MFMA: wave w computes output quarter w over K=256
    f32x4 oacc = {0.f,0.f,0.f,0.f};
    const int nsw = (l15&7)<<3;
    #pragma unroll
    for (int i=0;i<4;++i){
      bf16x8 fb0 = __builtin_bit_cast(bf16x8,
        *reinterpret_cast<const u16x8*>(&ob[l15*256 + ((i*64      + lg*8) ^ nsw)]));
      bf16x8 fb1 = __builtin_bit_cast(bf16x8,
        *reinterpret_cast<const u16x8*>(&ob[l15*256 + ((i*64 + 32 + lg*8) ^ nsw)]));
      oacc = mfma16(W2F[i*2+0], fb0, oacc);
      oacc = mfma16(W2F[i*2+1], fb1, oacc);
    }
    float4 o;
    o.x = oacc[0] + b2q.x + bf2f(tq[0]);
    o.y = oacc[1] + b2q.y + bf2f(tq[1]);
    o.z = oacc[2] + b2q.z + bf2f(tq[2]);
    o.w = oacc[3] + b2q.w + bf2f(tq[3]);
    *reinterpret_cast<float4*>(&out[gtok*64 + w*16 + lg*4]) = o;
  }
}

extern "C" void kernel_launch(void* const* d_in, const int* in_sizes, int n_in,
                              void* d_out, int out_size, void* d_ws, size_t ws_size,
                              hipStream_t stream)
{
  const float* x  =(const float*)d_in[0];
  const float* g1 =(const float*)d_in[3];
  const float* be1=(const float*)d_in[4];
  const float* Wk =(const float*)d_in[5];
  const float* bk =(const float*)d_in[6];
  const float* Wq =(const float*)d_in[7];
  const float* bq =(const float*)d_in[8];
  const float* Wv =(const float*)d_in[9];
  const float* bv =(const float*)d_in[10];
  const float* Wr =(const float*)d_in[11];
  const float* br =(const float*)d_in[12];
  const float* g2 =(const float*)d_in[13];
  const float* be2=(const float*)d_in[14];
  const float* W1 =(const float*)d_in[15];
  const float* b1 =(const float*)d_in[16];
  const float* dww=(const float*)d_in[17];
  const float* dwb=(const float*)d_in[18];
  const float* W2 =(const float*)d_in[19];
  const float* b2 =(const float*)d_in[20];
  float* outp = (float*)d_out;
  char* ws = (char*)d_ws;

  unsigned short* wfb    = (unsigned short*)ws;                 // 96KB
  unsigned short* ctxWrF = (unsigned short*)(ws + 98304);       // 128KB
  float* g_sump = (float*)(ws + 229376);                        // 128KB
  float* g_part = (float*)(ws + 393216);                        // 8MB
  unsigned short* g_txb = (unsigned short*)(ws + 16777216);     // 32MB bf16
  unsigned char* g_h    = (unsigned char*)(ws + 50331648);      // 68.2MB padded fp8
  unsigned char* zr     = (unsigned char*)(ws + 186646528);     // 33KB fp8 zero row
  float* dwp            = (float*)(ws + 186712064);             // 12KB repacked taps+bias

  hipLaunchKernelGGL(k0_wfrag, dim3(97), dim3(64), 0, stream, Wk, Wq, Wv, Wr, W1, W2, dww, dwb, dwp, wfb);
  hipLaunchKernelGGL(zhalo, dim3(1057), dim3(256), 0, stream, (unsigned*)g_h, (unsigned*)zr);
  hipLaunchKernelGGL(k1_ctx, dim3(512), dim3(256), 0, stream, x, g1, be1, bk, bv, wfb, g_part, g_sump);
  hipLaunchKernelGGL(k15_ctxwr, dim3(16), dim3(512), 0, stream, g_part, g_sump, Wr, ctxWrF);
  hipLaunchKernelGGL(k2_attn_ffn1, dim3(1024), dim3(256), 0, stream,
                     x, g1, be1, bq, br, g2, be2, b1, wfb, ctxWrF, g_txb, g_h);
  hipLaunchKernelGGL(k3_conv_ffn2, dim3(1024), dim3(256), 0, stream,
                     g_h, zr, dwp, b2, wfb, g_txb, outp);
}

// Round 10
// 208.322 us; speedup vs baseline: 1.6215x; 1.0078x over previous
//
#include <hip/hip_runtime.h>
#include <math.h>

typedef __bf16 bf16x8 __attribute__((ext_vector_type(8)));
typedef float f32x4 __attribute__((ext_vector_type(4)));
typedef float f32x2 __attribute__((ext_vector_type(2)));
typedef unsigned short u16x8 __attribute__((ext_vector_type(8)));
typedef unsigned short u16x4v __attribute__((ext_vector_type(4)));

constexpr int NIMG = 16384;   // H*W
constexpr int HPITCH = 130;   // padded row pitch (tokens) for g_h

__device__ __forceinline__ unsigned short f2bf(float f){
  unsigned u = __builtin_bit_cast(unsigned, f);
  u += 0x7fffu + ((u>>16)&1u);
  return (unsigned short)(u>>16);
}
__device__ __forceinline__ unsigned pack2(float a, float b){
  return (unsigned)f2bf(a) | ((unsigned)f2bf(b)<<16);
}
__device__ __forceinline__ float bf2f(unsigned short h){
  unsigned u = ((unsigned)h)<<16;
  return __builtin_bit_cast(float, u);
}
__device__ __forceinline__ bf16x8 ldfrag_g(const unsigned short* p){
  u16x8 v = *reinterpret_cast<const u16x8*>(p);
  return __builtin_bit_cast(bf16x8, v);
}
__device__ __forceinline__ f32x4 mfma16(bf16x8 a, bf16x8 b, f32x4 c){
  return __builtin_amdgcn_mfma_f32_16x16x32_bf16(a, b, c, 0, 0, 0);
}

// h-channel permutation: channel c lives at slot c' = (c&15)*16 + (c>>4).
// orig(c') = ((c'&15)<<4) | (c'>>4).  g_h stores fp8-e4m3 (1 B/ch).

// ============ k0: weights fp32 -> bf16 MFMA fragment layout (+ tap repack) ============
__global__ __launch_bounds__(64) void k0_wfrag(
  const float* __restrict__ Wk, const float* __restrict__ Wq,
  const float* __restrict__ Wv, const float* __restrict__ Wr,
  const float* __restrict__ W1, const float* __restrict__ W2,
  const float* __restrict__ dww, const float* __restrict__ dwb,
  float* __restrict__ dwp, unsigned short* __restrict__ wf)
{
  const int bid = blockIdx.x, l = threadIdx.x;
  if (bid == 96){
    // taps+bias keyed by permuted slot PAIR: dwp[cp*24 + j*2 + b] = tap j of
    // orig(2cp+b); dwp[cp*24+18+b] = bias.  (cp = 0..127)
    #pragma unroll
    for (int h=0; h<2; ++h){
      int cp = l + h*64;
      #pragma unroll
      for (int b=0; b<2; ++b){
        int slot = 2*cp + b;
        int f = ((slot&15)<<4) | (slot>>4);
        #pragma unroll
        for (int j=0;j<9;++j) dwp[cp*24 + j*2 + b] = dww[f*9+j];
        dwp[cp*24 + 18 + b] = dwb[f];
        dwp[cp*24 + 20 + b] = 0.f;
        dwp[cp*24 + 22 + b] = 0.f;
      }
    }
    return;
  }
  const float* src; int K, nt, ks; unsigned short* dst; bool perm = false;
  if (bid < 32){
    int w = bid>>3, f = bid&7;
    src = (w==0)?Wk:(w==1)?Wq:(w==2)?Wv:Wr;
    K = 64; nt = f>>1; ks = f&1;
    dst = wf + w*4096 + f*512;
  } else if (bid < 64){
    int f = bid-32; src = W1; K = 64; nt = f>>1; ks = f&1;
    dst = wf + 16384 + f*512;
  } else {
    int f = bid-64; src = W2; K = 256; nt = f>>3; ks = f&7;
    dst = wf + 32768 + f*512; perm = true;   // k index = permuted slot c'
  }
  u16x8 v;
  #pragma unroll
  for (int j=0;j<8;++j){
    int k = ks*32 + (l>>4)*8 + j;
    if (perm) k = ((k&15)<<4) | (k>>4);
    int n = nt*16 + (l&15);
    v[j] = f2bf(src[n*K + k]);
  }
  *reinterpret_cast<u16x8*>(dst + l*8) = v;
}

// ============ zhalo: zero g_h halo columns (fp8) + shared zero-row ============
__global__ __launch_bounds__(256) void zhalo(unsigned* __restrict__ gh, unsigned* __restrict__ zr){
  int idx = blockIdx.x*256 + threadIdx.x;
  if (idx < 262144){
    int ch = idx & 63;           // dword within token (64 dwords = 256 fp8)
    int pos = idx >> 6;
    int side = pos & 1, row = pos >> 1;
    gh[(size_t)(row*HPITCH + side*(HPITCH-1))*64 + ch] = 0;
  } else {
    int j = idx - 262144;
    if (j < 8320) zr[j] = 0;     // 130 tok x 256 fp8 = 8320 dwords
  }
}

// ============ k1: LN1 + K/V proj (MFMA) + ctx accumulation (MFMA, LDS-transpose) ============
__global__ __launch_bounds__(256,2) void k1_ctx(
  const float* __restrict__ x, const float* __restrict__ g1, const float* __restrict__ be1,
  const float* __restrict__ bk, const float* __restrict__ bv,
  const unsigned short* __restrict__ wf,
  float* __restrict__ g_part, float* __restrict__ g_sump)
{
  __shared__ unsigned short tiles[4][4096];
  __shared__ float ctx_l[64*68];
  __shared__ float ssum_l[4][64];
  const int t = threadIdx.x, wid = t>>6, l = t&63;
  const int lg = l>>4, l15 = l&15;
  unsigned short* tile = tiles[wid];
  const int tok0 = blockIdx.x*512 + wid*128;

  bf16x8 WkF[8], WvF[8];
  #pragma unroll
  for (int f=0; f<8; ++f){
    WkF[f] = ldfrag_g(wf +    0 + f*512 + l*8);
    WvF[f] = ldfrag_g(wf + 8192 + f*512 + l*8);
  }
  float4 g1v  = *reinterpret_cast<const float4*>(&g1[l15*4]);
  float4 be1v = *reinterpret_cast<const float4*>(&be1[l15*4]);
  float bkv[4], bvv[4];
  #pragma unroll
  for (int ct=0; ct<4; ++ct){ bkv[ct]=bk[ct*16+l15]; bvv[ct]=bv[ct*16+l15]; }

  f32x4 acc[4][4];
  #pragma unroll
  for (int a=0;a<4;++a)
    #pragma unroll
    for (int b=0;b<4;++b) acc[a][b] = (f32x4){0.f,0.f,0.f,0.f};
  float sume[4] = {0.f,0.f,0.f,0.f};

  for (int tb=0; tb<2; ++tb){
    const int tbase = tok0 + tb*64;
    #pragma unroll
    for (int it=0; it<16; ++it){
      int row = it*4 + lg;
      float4 xv = *reinterpret_cast<const float4*>(&x[(size_t)(tbase+row)*64 + l15*4]);
      float s1 = xv.x+xv.y+xv.z+xv.w;
      float s2 = xv.x*xv.x + xv.y*xv.y + xv.z*xv.z + xv.w*xv.w;
      #pragma unroll
      for (int off=1; off<16; off<<=1){ s1 += __shfl_xor(s1,off,64); s2 += __shfl_xor(s2,off,64); }
      float mu = s1*(1.f/64.f);
      float rs = rsqrtf(s2*(1.f/64.f) - mu*mu + 1e-5f);
      uint2 pk = { pack2((xv.x-mu)*rs*g1v.x + be1v.x, (xv.y-mu)*rs*g1v.y + be1v.y),
                   pack2((xv.z-mu)*rs*g1v.z + be1v.z, (xv.w-mu)*rs*g1v.w + be1v.w) };
      *reinterpret_cast<uint2*>(&tile[row*64 + ((l15*4) ^ ((row&7)<<3))]) = pk;
    }
    bf16x8 aF[4][2];
    #pragma unroll
    for (int mt=0;mt<4;++mt){
      int row = mt*16+l15, sw=(row&7)<<3, ab=row*64;
      aF[mt][0] = __builtin_bit_cast(bf16x8, *reinterpret_cast<const u16x8*>(tile+ab+((     lg*8)^sw)));
      aF[mt][1] = __builtin_bit_cast(bf16x8, *reinterpret_cast<const u16x8*>(tile+ab+((32 + lg*8)^sw)));
    }
    #pragma unroll
    for (int half=0; half<2; ++half){
      #pragma unroll
      for (int m2=0;m2<2;++m2){
        const int mt = half*2+m2;
        #pragma unroll
        for (int ct=0;ct<4;++ct){
          f32x4 z = {0.f,0.f,0.f,0.f};
          z = mfma16(aF[mt][0], WkF[ct*2+0], z);
          z = mfma16(aF[mt][1], WkF[ct*2+1], z);
          float e0=__expf(z[0]+bkv[ct]), e1=__expf(z[1]+bkv[ct]);
          float e2=__expf(z[2]+bkv[ct]), e3=__expf(z[3]+bkv[ct]);
          sume[ct] += (e0+e1)+(e2+e3);
          const int c = ct*16+l15, sw = (c&7)<<3;
          const int cb = m2*16+lg*4;
          uint2 pe = { pack2(e0,e1), pack2(e2,e3) };
          *reinterpret_cast<uint2*>(&tile[c*64 + (cb ^ sw)]) = pe;
          f32x4 w = {0.f,0.f,0.f,0.f};
          w = mfma16(aF[mt][0], WvF[ct*2+0], w);
          w = mfma16(aF[mt][1], WvF[ct*2+1], w);
          uint2 pv = { pack2(w[0]+bvv[ct], w[1]+bvv[ct]), pack2(w[2]+bvv[ct], w[3]+bvv[ct]) };
          *reinterpret_cast<uint2*>(&tile[c*64 + ((32+cb) ^ sw)]) = pv;
        }
      }
      bf16x8 eA[4], vB[4];
      #pragma unroll
      for (int cm=0;cm<4;++cm){
        int row = cm*16+l15, sw=(row&7)<<3;
        eA[cm] = __builtin_bit_cast(bf16x8, *reinterpret_cast<const u16x8*>(tile + row*64 + ((     lg*8)^sw)));
        vB[cm] = __builtin_bit_cast(bf16x8, *reinterpret_cast<const u16x8*>(tile + row*64 + ((32 + lg*8)^sw)));
      }
      #pragma unroll
      for (int cm=0; cm<4; ++cm)
        #pragma unroll
        for (int jn=0; jn<4; ++jn)
          acc[cm][jn] = mfma16(eA[cm], vB[jn], acc[cm][jn]);
    }
  }
  #pragma unroll
  for (int ct=0; ct<4; ++ct){
    float s = sume[ct];
    s += __shfl_xor(s,16,64); s += __shfl_xor(s,32,64);
    if (lg==0) ssum_l[wid][ct*16+l15] = s;
  }
  #define CTX_RED(OP) \
    _Pragma("unroll") for (int cm=0;cm<4;++cm) \
    _Pragma("unroll") for (int jn=0;jn<4;++jn) \
    _Pragma("unroll") for (int r=0;r<4;++r) \
      ctx_l[(cm*16+lg*4+r)*68 + jn*16+l15] OP acc[cm][jn][r];
  if (wid==0){ CTX_RED(=) }  __syncthreads();
  if (wid==1){ CTX_RED(+=) } __syncthreads();
  if (wid==2){ CTX_RED(+=) } __syncthreads();
  if (wid==3){ CTX_RED(+=) } __syncthreads();
  #undef CTX_RED
  for (int i=t; i<4096; i+=256)
    g_part[(size_t)blockIdx.x*4096 + i] = ctx_l[(i>>6)*68 + (i&63)];
  if (t<64)
    g_sump[blockIdx.x*64 + t] = ssum_l[0][t]+ssum_l[1][t]+ssum_l[2][t]+ssum_l[3][t];
}

// ============ k15: reduce partials; ctxWr = (ctx_norm @ Wr^T) -> bf16 frags ============
__global__ __launch_bounds__(512) void k15_ctxwr(
  const float* __restrict__ g_part, const float* __restrict__ g_sump,
  const float* __restrict__ Wr, unsigned short* __restrict__ ctxWrF)
{
  __shared__ float sctx[4096];
  __shared__ float sWr[4096];
  __shared__ float sinv[64];
  const int b = blockIdx.x, t = threadIdx.x;
  if (t<64){
    float s=0.f;
    #pragma unroll 8
    for (int p=0;p<32;++p) s += g_sump[(b*32+p)*64 + t];
    sinv[t] = 1.f/s;
  }
  for (int idx=t; idx<4096; idx+=512){
    float s=0.f;
    #pragma unroll 8
    for (int p=0;p<32;++p) s += g_part[(size_t)(b*32+p)*4096 + idx];
    sctx[idx] = s;
  }
  __syncthreads();
  {
    int c = t>>3, d0 = (t&7)*8;
    float invc = sinv[c];
    #pragma unroll
    for (int dd=0; dd<8; ++dd){
      int d = d0+dd; float s = 0.f;
      #pragma unroll
      for (int v=0; v<64; ++v) s += sctx[c*64+v]*Wr[d*64+v];
      sWr[c*64+d] = s*invc;
    }
  }
  __syncthreads();
  {
    int f = t>>6, l = t&63, nt = f>>1, ks = f&1;
    u16x8 v;
    #pragma unroll
    for (int j=0;j<8;++j){
      int k = ks*32 + (l>>4)*8 + j;
      int n = nt*16 + (l&15);
      v[j] = f2bf(sWr[k*64+n]);
    }
    *reinterpret_cast<u16x8*>(ctxWrF + b*4096 + f*512 + l*8) = v;
  }
}

// ============ k2: LN1 + q-softmax + attn + residual + LN2 + W1 -> fp8 g_h ============
__global__ __launch_bounds__(256,2) void k2_attn_ffn1(
  const float* __restrict__ x,
  const float* __restrict__ g1, const float* __restrict__ be1,
  const float* __restrict__ bq, const float* __restrict__ br,
  const float* __restrict__ g2, const float* __restrict__ be2,
  const float* __restrict__ b1,
  const unsigned short* __restrict__ wf,
  const unsigned short* __restrict__ ctxWrF,
  unsigned short* __restrict__ g_txb, unsigned char* __restrict__ g_h)
{
  __shared__ unsigned short tiles[4][4096];
  const int t = threadIdx.x, wid = t>>6, l = t&63;
  const int l15 = l&15, lg = l>>4;
  unsigned short* tile = tiles[wid];
  const int tok0 = (blockIdx.x*4 + wid)*64;
  const int img  = blockIdx.x>>6;
  const int yrow = (tok0>>7)&127;
  const int xb   = tok0&127;
  const size_t hbase = ((size_t)(img*128 + yrow)*HPITCH + 1 + xb)*256;  // BYTES (fp8)

  bf16x8 WqF[8], CWF[8];
  #pragma unroll
  for (int f=0; f<8; ++f){
    WqF[f] = ldfrag_g(wf + 4096 + f*512 + l*8);
    CWF[f] = ldfrag_g(ctxWrF + img*4096 + f*512 + l*8);
  }
  float4 g1v  = *reinterpret_cast<const float4*>(&g1[l15*4]);
  float4 be1v = *reinterpret_cast<const float4*>(&be1[l15*4]);
  float bqv[4], brv[4], g2v[4], be2v[4];
  #pragma unroll
  for (int nt=0; nt<4; ++nt){
    bqv[nt]=bq[nt*16+l15]; brv[nt]=br[nt*16+l15];
    g2v[nt]=g2[nt*16+l15]; be2v[nt]=be2[nt*16+l15];
  }
  float b1v[16];
  #pragma unroll
  for (int i=0;i<16;++i) b1v[i]=b1[i*16+l15];

  // ---- LN1 -> swizzled bf16 tile ----
  #pragma unroll
  for (int it=0; it<16; ++it){
    int row = it*4 + lg;
    float4 xv = *reinterpret_cast<const float4*>(&x[(size_t)(tok0+row)*64 + l15*4]);
    float s1 = xv.x+xv.y+xv.z+xv.w;
    float s2 = xv.x*xv.x + xv.y*xv.y + xv.z*xv.z + xv.w*xv.w;
    #pragma unroll
    for (int off=1; off<16; off<<=1){ s1 += __shfl_xor(s1,off,64); s2 += __shfl_xor(s2,off,64); }
    float mu = s1*(1.f/64.f);
    float rs = rsqrtf(s2*(1.f/64.f) - mu*mu + 1e-5f);
    uint2 pk = { pack2((xv.x-mu)*rs*g1v.x + be1v.x, (xv.y-mu)*rs*g1v.y + be1v.y),
                 pack2((xv.z-mu)*rs*g1v.z + be1v.z, (xv.w-mu)*rs*g1v.w + be1v.w) };
    *reinterpret_cast<uint2*>(&tile[row*64 + ((l15*4) ^ ((row&7)<<3))]) = pk;
  }

  // ---- phase A: per m-tile attn chain; leaves n2 in the tile ----
  for (int mt=0; mt<4; ++mt){
    const int arow = mt*16 + l15;
    const int asw  = (arow&7)<<3;
    const int abase= arow*64;
    bf16x8 a0 = __builtin_bit_cast(bf16x8, *reinterpret_cast<const u16x8*>(tile + abase + ((     lg*8) ^ asw)));
    bf16x8 a1 = __builtin_bit_cast(bf16x8, *reinterpret_cast<const u16x8*>(tile + abase + ((32 + lg*8) ^ asw)));
    f32x4 qa[4];
    #pragma unroll
    for (int nt=0; nt<4; ++nt){
      f32x4 z = {0.f,0.f,0.f,0.f};
      z = mfma16(a0, WqF[nt*2+0], z);
      z = mfma16(a1, WqF[nt*2+1], z);
      qa[nt] = z;
    }
    #pragma unroll
    for (int nt=0; nt<4; ++nt)
      #pragma unroll
      for (int r=0; r<4; ++r) qa[nt][r] += bqv[nt];
    float mx[4];
    #pragma unroll
    for (int r=0;r<4;++r) mx[r] = fmaxf(fmaxf(qa[0][r],qa[1][r]), fmaxf(qa[2][r],qa[3][r]));
    #pragma unroll
    for (int off=1; off<16; off<<=1)
      #pragma unroll
      for (int r=0;r<4;++r) mx[r] = fmaxf(mx[r], __shfl_xor(mx[r], off, 64));
    float sm[4] = {0.f,0.f,0.f,0.f};
    #pragma unroll
    for (int nt=0;nt<4;++nt)
      #pragma unroll
      for (int r=0;r<4;++r){ float e = __expf(qa[nt][r]-mx[r]); qa[nt][r]=e; sm[r]+=e; }
    #pragma unroll
    for (int off=1; off<16; off<<=1)
      #pragma unroll
      for (int r=0;r<4;++r) sm[r] += __shfl_xor(sm[r], off, 64);
    float inv[4];
    #pragma unroll
    for (int r=0;r<4;++r) inv[r] = 1.f/sm[r];
    #pragma unroll
    for (int nt=0;nt<4;++nt)
      #pragma unroll
      for (int r=0;r<4;++r){
        int row = mt*16 + lg*4 + r, col = nt*16 + l15;
        tile[row*64 + (col ^ ((row&7)<<3))] = f2bf(qa[nt][r]*inv[r]);
      }
    bf16x8 p0 = __builtin_bit_cast(bf16x8, *reinterpret_cast<const u16x8*>(tile + abase + ((     lg*8) ^ asw)));
    bf16x8 p1 = __builtin_bit_cast(bf16x8, *reinterpret_cast<const u16x8*>(tile + abase + ((32 + lg*8) ^ asw)));
    f32x4 ao[4];
    #pragma unroll
    for (int nt=0; nt<4; ++nt){
      f32x4 z = {0.f,0.f,0.f,0.f};
      z = mfma16(p0, CWF[nt*2+0], z);
      z = mfma16(p1, CWF[nt*2+1], z);
      ao[nt] = z;
    }
    float txv[4][4];
    float s1v[4] = {0.f,0.f,0.f,0.f}, s2v[4] = {0.f,0.f,0.f,0.f};
    #pragma unroll
    for (int nt=0;nt<4;++nt)
      #pragma unroll
      for (int r=0;r<4;++r){
        size_t row = (size_t)(tok0 + mt*16 + lg*4 + r);
        float v = ao[nt][r] + brv[nt] + x[row*64 + nt*16+l15];
        g_txb[row*64 + nt*16+l15] = f2bf(v);
        txv[nt][r] = v; s1v[r] += v; s2v[r] += v*v;
      }
    #pragma unroll
    for (int off=1; off<16; off<<=1)
      #pragma unroll
      for (int r=0;r<4;++r){ s1v[r] += __shfl_xor(s1v[r], off, 64); s2v[r] += __shfl_xor(s2v[r], off, 64); }
    #pragma unroll
    for (int r=0;r<4;++r){
      float mu2 = s1v[r]*(1.f/64.f);
      float rs  = rsqrtf(s2v[r]*(1.f/64.f) - mu2*mu2 + 1e-5f);
      s1v[r] = mu2; s2v[r] = rs;
    }
    #pragma unroll
    for (int nt=0;nt<4;++nt)
      #pragma unroll
      for (int r=0;r<4;++r){
        int row = mt*16 + lg*4 + r, col = nt*16 + l15;
        float n2 = (txv[nt][r]-s1v[r])*s2v[r]*g2v[nt] + be2v[nt];
        tile[row*64 + (col ^ ((row&7)<<3))] = f2bf(n2);
      }
  }

  // ---- phase B: h = n2 @ W1^T + b1; mt-outer, fp8-packed PERMUTED uint4 stores ----
  // channel c = nt2*16 + l15 stored at slot c' = l15*16 + nt2  => 16 contiguous fp8/thread/row.
  for (int mt=0; mt<4; ++mt){
    const int arow = mt*16 + l15;
    const int asw  = (arow&7)<<3;
    const int abase= arow*64;
    bf16x8 n20 = __builtin_bit_cast(bf16x8, *reinterpret_cast<const u16x8*>(tile + abase + ((     lg*8) ^ asw)));
    bf16x8 n21 = __builtin_bit_cast(bf16x8, *reinterpret_cast<const u16x8*>(tile + abase + ((32 + lg*8) ^ asw)));
    unsigned hq[4][4];
    #pragma unroll
    for (int np=0; np<8; ++np){
      bf16x8 wa0 = ldfrag_g(wf + 16384 + (np*4+0)*512 + l*8);
      bf16x8 wa1 = ldfrag_g(wf + 16384 + (np*4+1)*512 + l*8);
      bf16x8 wb0 = ldfrag_g(wf + 16384 + (np*4+2)*512 + l*8);
      bf16x8 wb1 = ldfrag_g(wf + 16384 + (np*4+3)*512 + l*8);
      float ba = b1v[np*2], bb = b1v[np*2+1];
      f32x4 ha = {ba,ba,ba,ba};
      ha = mfma16(n20, wa0, ha);
      ha = mfma16(n21, wa1, ha);
      f32x4 hb = {bb,bb,bb,bb};
      hb = mfma16(n20, wb0, hb);
      hb = mfma16(n21, wb1, hb);
      const int d = np>>1;
      if ((np&1)==0){
        #pragma unroll
        for (int r=0;r<4;++r)
          hq[r][d] = (unsigned)__builtin_amdgcn_cvt_pk_fp8_f32(ha[r], hb[r], 0, false);
      } else {
        #pragma unroll
        for (int r=0;r<4;++r)
          hq[r][d] = (unsigned)__builtin_amdgcn_cvt_pk_fp8_f32(ha[r], hb[r], (int)hq[r][d], true);
      }
    }
    #pragma unroll
    for (int r=0;r<4;++r){
      const size_t ro = hbase + (size_t)(mt*16+lg*4+r)*256 + l15*16;
      uint4 v = { hq[r][0], hq[r][1], hq[r][2], hq[r][3] };
      *reinterpret_cast<uint4*>(g_h + ro) = v;
    }
  }
}

// ============ k3: depthwise conv3x3 + GELU + W2 — fp8 ring, 2ch/lane packed conv ============
// Block = 16 x-tok x 16 y-rows, 256 thr. 4-slot LDS FP8 row ring (65-dword
// pitch, 18.7 KB). Conv: lane owns channel pair (2cp,2cp+1), 8 positions
// (waves 0-1: pos 0-7, waves 2-3: pos 8-15); v_pk_fma_f32 + cvt_pk_f32_fp8.
// Staging: raw fp8 dword stores (no convert). One barrier per y-iter.
__global__ __launch_bounds__(256,4) void k3_conv_ffn2(
  const unsigned char* __restrict__ g_h,
  const unsigned char* __restrict__ zrow,
  const float* __restrict__ dwp,
  const float* __restrict__ b2,
  const unsigned short* __restrict__ wf,
  const unsigned short* __restrict__ g_txb, float* __restrict__ out)
{
  __shared__ unsigned ring[4][1170];        // 4 slots x 18 pos x 65-dword pitch = 18.7 KB
  __shared__ unsigned short obuf[2][4096];  // double-buffered 16tok x 256ch = 16 KB
  const int t = threadIdx.x, w = t>>6, l = t&63;
  const int l15 = l&15, lg = l>>4;
  const int bid = (blockIdx.x & 7)*128 + (blockIdx.x >> 3);   // XCD-chunked remap
  const int img = bid>>6;
  const int r6  = bid&63;
  const int y0  = (r6>>3)*16, x0 = (r6&7)*16;

  // conv: lane's channel pair cp (slots 2cp, 2cp+1); position group pg
  const int cp = t & 127;
  const int pg = t >> 7;
  f32x2 tp[9];
  #pragma unroll
  for (int j=0;j<9;++j)
    tp[j] = *reinterpret_cast<const f32x2*>(&dwp[cp*24 + j*2]);
  const f32x2 cb2 = *reinterpret_cast<const f32x2*>(&dwp[cp*24 + 18]);

  // W2 frags for output quarter ntc = w
  bf16x8 W2F[8];
  #pragma unroll
  for (int q=0;q<8;++q)
    W2F[q] = ldfrag_g(wf + 32768 + (w*8 + q)*512 + l*8);
  const float4 b2q = *reinterpret_cast<const float4*>(&b2[w*16 + lg*4]);

  // staging map: thread t stages position pi = 1+(t&15), channels c0..c0+15
  const int pi = 1 + (t&15);
  const int c0 = (t>>4)*16;

  auto rowsrc = [&](int ri) -> const unsigned char* {
    return (ri>=0 && ri<128)
      ? g_h + ((size_t)(img*128+ri)*HPITCH + x0)*256
      : zrow + x0*256;
  };
  auto ldrow = [&](int ri, uint4* m, unsigned* h){
    const unsigned char* src = rowsrc(ri);
    *m = *reinterpret_cast<const uint4*>(src + pi*256 + c0);
    if (t < 128){
      int ph = (t<64)?0:17, dh = t&63;
      *h = reinterpret_cast<const unsigned*>(src + ph*256)[dh];
    }
  };
  auto wrrow = [&](int sl, uint4 m, unsigned h){
    unsigned* rg = ring[sl];
    const int base = pi*65 + (c0>>2);
    rg[base+0] = m.x; rg[base+1] = m.y; rg[base+2] = m.z; rg[base+3] = m.w;
    if (t < 128){
      int ph = (t<64)?0:17, dh = t&63;
      rg[ph*65 + dh] = h;
    }
  };

  // prologue: stage rows y0-1, y0, y0+1 into slots 0,1,2
  {
    uint4 m0,m1,m2; unsigned h0=0,h1=0,h2=0;
    ldrow(y0-1,&m0,&h0); ldrow(y0,&m1,&h1); ldrow(y0+1,&m2,&h2);
    wrrow(0,m0,h0); wrrow(1,m1,h1); wrrow(2,m2,h2);
  }
  __syncthreads();

  const f32x2 kC0 = {-2.3022082f,-2.3022082f};
  const f32x2 kC1 = {-0.1029432f,-0.1029432f};

  for (int yy=0; yy<16; ++yy){
    const int gy = y0 + yy;
    // T14 issue-early: fp8 loads of row gy+2 into regs
    uint4 rm; unsigned rh = 0;
    ldrow(gy+2, &rm, &rh);
    // epilogue residual prefetch
    const size_t gtok = (size_t)img*16384 + (size_t)gy*128 + x0 + l15;
    const u16x4v tq = *reinterpret_cast<const u16x4v*>(&g_txb[gtok*64 + w*16 + lg*4]);

    // conv from fp8 ring (rows y-1,y,y+1 = slots yy, yy+1, yy+2 mod 4)
    {
      const unsigned short* rA = reinterpret_cast<const unsigned short*>(ring[(yy  )&3]);
      const unsigned short* rB = reinterpret_cast<const unsigned short*>(ring[(yy+1)&3]);
      const unsigned short* rC = reinterpret_cast<const unsigned short*>(ring[(yy+2)&3]);
      unsigned short* ob = obuf[yy&1];
      // u16 index for ring position ridx: ridx*130 + cp (2 fp8 = lane's pair)
      const int rb = pg*8;
      f32x2 PA = __builtin_amdgcn_cvt_pk_f32_fp8((int)rA[(rb  )*130 + cp], false);
      f32x2 PB = __builtin_amdgcn_cvt_pk_f32_fp8((int)rB[(rb  )*130 + cp], false);
      f32x2 PC = __builtin_amdgcn_cvt_pk_f32_fp8((int)rC[(rb  )*130 + cp], false);
      f32x2 CA = __builtin_amdgcn_cvt_pk_f32_fp8((int)rA[(rb+1)*130 + cp], false);
      f32x2 CB = __builtin_amdgcn_cvt_pk_f32_fp8((int)rB[(rb+1)*130 + cp], false);
      f32x2 CC = __builtin_amdgcn_cvt_pk_f32_fp8((int)rC[(rb+1)*130 + cp], false);
      #pragma unroll
      for (int i=0;i<8;++i){
        const int ro = (rb+i+2)*130 + cp;
        f32x2 NA = __builtin_amdgcn_cvt_pk_f32_fp8((int)rA[ro], false);
        f32x2 NB = __builtin_amdgcn_cvt_pk_f32_fp8((int)rB[ro], false);
        f32x2 NC = __builtin_amdgcn_cvt_pk_f32_fp8((int)rC[ro], false);
        f32x2 a = cb2;
        a += tp[0]*PA; a += tp[1]*CA; a += tp[2]*NA;
        a += tp[3]*PB; a += tp[4]*CB; a += tp[5]*NB;
        a += tp[6]*PC; a += tp[7]*CC; a += tp[8]*NC;
        f32x2 u = a*a;
        f32x2 wv = u*kC1 + kC0;
        f32x2 arg = a*wv;
        f32x2 e;
        e[0]=__builtin_amdgcn_exp2f(arg[0]); e[1]=__builtin_amdgcn_exp2f(arg[1]);
        f32x2 den = e + (f32x2){1.f,1.f};
        f32x2 rc;
        rc[0]=__builtin_amdgcn_rcpf(den[0]); rc[1]=__builtin_amdgcn_rcpf(den[1]);
        f32x2 g = a*rc;
        unsigned pk;
        asm("v_cvt_pk_bf16_f32 %0, %1, %2" : "=v"(pk) : "v"(g[0]), "v"(g[1]));
        const int p = rb + i;
        *reinterpret_cast<unsigned*>(&ob[p*256 + ((2*cp) ^ ((p&7)<<3))]) = pk;
        PA=CA; PB=CB; PC=CC; CA=NA; CB=NB; CC=NC;
      }
    }

    // write-late: staged fp8 row -> ring slot (yy+3)&3 (raw dwords)
    wrrow((yy+3)&3, rm, rh);
    __syncthreads();

    // W2 MFMA: wave w computes output quarter w over K=256
    f32x4 oacc = {0.f,0.f,0.f,0.f};
    const int nsw = (l15&7)<<3;
    const unsigned short* ob = obuf[yy&1];
    #pragma unroll
    for (int i=0;i<4;++i){
      bf16x8 fb0 = __builtin_bit_cast(bf16x8,
        *reinterpret_cast<const u16x8*>(&ob[l15*256 + ((i*64      + lg*8) ^ nsw)]));
      bf16x8 fb1 = __builtin_bit_cast(bf16x8,
        *reinterpret_cast<const u16x8*>(&ob[l15*256 + ((i*64 + 32 + lg*8) ^ nsw)]));
      oacc = mfma16(W2F[i*2+0], fb0, oacc);
      oacc = mfma16(W2F[i*2+1], fb1, oacc);
    }
    float4 o;
    o.x = oacc[0] + b2q.x + bf2f(tq[0]);
    o.y = oacc[1] + b2q.y + bf2f(tq[1]);
    o.z = oacc[2] + b2q.z + bf2f(tq[2]);
    o.w = oacc[3] + b2q.w + bf2f(tq[3]);
    *reinterpret_cast<float4*>(&out[gtok*64 + w*16 + lg*4]) = o;
  }
}

extern "C" void kernel_launch(void* const* d_in, const int* in_sizes, int n_in,
                              void* d_out, int out_size, void* d_ws, size_t ws_size,
                              hipStream_t stream)
{
  const float* x  =(const float*)d_in[0];
  const float* g1 =(const float*)d_in[3];
  const float* be1=(const float*)d_in[4];
  const float* Wk =(const float*)d_in[5];
  const float* bk =(const float*)d_in[6];
  const float* Wq =(const float*)d_in[7];
  const float* bq =(const float*)d_in[8];
  const float* Wv =(const float*)d_in[9];
  const float* bv =(const float*)d_in[10];
  const float* Wr =(const float*)d_in[11];
  const float* br =(const float*)d_in[12];
  const float* g2 =(const float*)d_in[13];
  const float* be2=(const float*)d_in[14];
  const float* W1 =(const float*)d_in[15];
  const float* b1 =(const float*)d_in[16];
  const float* dww=(const float*)d_in[17];
  const float* dwb=(const float*)d_in[18];
  const float* W2 =(const float*)d_in[19];
  const float* b2 =(const float*)d_in[20];
  float* outp = (float*)d_out;
  char* ws = (char*)d_ws;

  unsigned short* wfb    = (unsigned short*)ws;                 // 96KB
  unsigned short* ctxWrF = (unsigned short*)(ws + 98304);       // 128KB
  float* g_sump = (float*)(ws + 229376);                        // 128KB
  float* g_part = (float*)(ws + 393216);                        // 8MB
  unsigned short* g_txb = (unsigned short*)(ws + 16777216);     // 32MB bf16
  unsigned char* g_h    = (unsigned char*)(ws + 50331648);      // 68.2MB padded fp8
  unsigned char* zr     = (unsigned char*)(ws + 186646528);     // 33KB fp8 zero row
  float* dwp            = (float*)(ws + 186712064);             // 12KB repacked taps+bias

  hipLaunchKernelGGL(k0_wfrag, dim3(97), dim3(64), 0, stream, Wk, Wq, Wv, Wr, W1, W2, dww, dwb, dwp, wfb);
  hipLaunchKernelGGL(zhalo, dim3(1057), dim3(256), 0, stream, (unsigned*)g_h, (unsigned*)zr);
  hipLaunchKernelGGL(k1_ctx, dim3(512), dim3(256), 0, stream, x, g1, be1, bk, bv, wfb, g_part, g_sump);
  hipLaunchKernelGGL(k15_ctxwr, dim3(16), dim3(512), 0, stream, g_part, g_sump, Wr, ctxWrF);
  hipLaunchKernelGGL(k2_attn_ffn1, dim3(1024), dim3(256), 0, stream,
                     x, g1, be1, bq, br, g2, be2, b1, wfb, ctxWrF, g_txb, g_h);
  hipLaunchKernelGGL(k3_conv_ffn2, dim3(1024), dim3(256), 0, stream,
                     g_h, zr, dwp, b2, wfb, g_txb, outp);
}

// Round 11
// 203.290 us; speedup vs baseline: 1.6617x; 1.0248x over previous
//
#include <hip/hip_runtime.h>
#include <math.h>

typedef __bf16 bf16x8 __attribute__((ext_vector_type(8)));
typedef float f32x4 __attribute__((ext_vector_type(4)));
typedef float f32x2 __attribute__((ext_vector_type(2)));
typedef unsigned short u16x8 __attribute__((ext_vector_type(8)));
typedef unsigned short u16x4v __attribute__((ext_vector_type(4)));

constexpr int NIMG = 16384;   // H*W
constexpr int HPITCH = 130;   // padded row pitch (tokens) for g_h

__device__ __forceinline__ unsigned short f2bf(float f){
  unsigned u = __builtin_bit_cast(unsigned, f);
  u += 0x7fffu + ((u>>16)&1u);
  return (unsigned short)(u>>16);
}
__device__ __forceinline__ unsigned pack2(float a, float b){
  return (unsigned)f2bf(a) | ((unsigned)f2bf(b)<<16);
}
__device__ __forceinline__ float bf2f(unsigned short h){
  unsigned u = ((unsigned)h)<<16;
  return __builtin_bit_cast(float, u);
}
__device__ __forceinline__ bf16x8 ldfrag_g(const unsigned short* p){
  u16x8 v = *reinterpret_cast<const u16x8*>(p);
  return __builtin_bit_cast(bf16x8, v);
}
__device__ __forceinline__ f32x4 mfma16(bf16x8 a, bf16x8 b, f32x4 c){
  return __builtin_amdgcn_mfma_f32_16x16x32_bf16(a, b, c, 0, 0, 0);
}

// h-channel permutation: channel c lives at slot c' = (c&15)*16 + (c>>4).
// orig(c') = ((c'&15)<<4) | (c'>>4).  g_h stores fp8-e4m3 (1 B/ch).

// ============ k0: weights fp32 -> bf16 MFMA fragment layout (+ tap repack) ============
__global__ __launch_bounds__(64) void k0_wfrag(
  const float* __restrict__ Wk, const float* __restrict__ Wq,
  const float* __restrict__ Wv, const float* __restrict__ Wr,
  const float* __restrict__ W1, const float* __restrict__ W2,
  const float* __restrict__ dww, const float* __restrict__ dwb,
  float* __restrict__ dwp, unsigned short* __restrict__ wf)
{
  const int bid = blockIdx.x, l = threadIdx.x;
  if (bid == 96){
    // taps+bias keyed by permuted slot PAIR: dwp[cp*24 + j*2 + b] = tap j of
    // orig(2cp+b); dwp[cp*24+18+b] = bias.  (cp = 0..127)
    #pragma unroll
    for (int h=0; h<2; ++h){
      int cp = l + h*64;
      #pragma unroll
      for (int b=0; b<2; ++b){
        int slot = 2*cp + b;
        int f = ((slot&15)<<4) | (slot>>4);
        #pragma unroll
        for (int j=0;j<9;++j) dwp[cp*24 + j*2 + b] = dww[f*9+j];
        dwp[cp*24 + 18 + b] = dwb[f];
        dwp[cp*24 + 20 + b] = 0.f;
        dwp[cp*24 + 22 + b] = 0.f;
      }
    }
    return;
  }
  const float* src; int K, nt, ks; unsigned short* dst; bool perm = false;
  if (bid < 32){
    int w = bid>>3, f = bid&7;
    src = (w==0)?Wk:(w==1)?Wq:(w==2)?Wv:Wr;
    K = 64; nt = f>>1; ks = f&1;
    dst = wf + w*4096 + f*512;
  } else if (bid < 64){
    int f = bid-32; src = W1; K = 64; nt = f>>1; ks = f&1;
    dst = wf + 16384 + f*512;
  } else {
    int f = bid-64; src = W2; K = 256; nt = f>>3; ks = f&7;
    dst = wf + 32768 + f*512; perm = true;   // k index = permuted slot c'
  }
  u16x8 v;
  #pragma unroll
  for (int j=0;j<8;++j){
    int k = ks*32 + (l>>4)*8 + j;
    if (perm) k = ((k&15)<<4) | (k>>4);
    int n = nt*16 + (l&15);
    v[j] = f2bf(src[n*K + k]);
  }
  *reinterpret_cast<u16x8*>(dst + l*8) = v;
}

// ============ zhalo: zero g_h halo columns (fp8) + shared zero-row ============
__global__ __launch_bounds__(256) void zhalo(unsigned* __restrict__ gh, unsigned* __restrict__ zr){
  int idx = blockIdx.x*256 + threadIdx.x;
  if (idx < 262144){
    int ch = idx & 63;           // dword within token (64 dwords = 256 fp8)
    int pos = idx >> 6;
    int side = pos & 1, row = pos >> 1;
    gh[(size_t)(row*HPITCH + side*(HPITCH-1))*64 + ch] = 0;
  } else {
    int j = idx - 262144;
    if (j < 8320) zr[j] = 0;     // 130 tok x 256 fp8 = 8320 dwords
  }
}

// ============ k1: LN1 + K/V proj (MFMA) + ctx accumulation ============
// Grid 1024 (256 tokens/block, 64/wave) for 4 blocks/CU TLP. Reduction
// buffers alias the (dead-by-then) tiles LDS: block LDS = 32 KB.
__global__ __launch_bounds__(256,2) void k1_ctx(
  const float* __restrict__ x, const float* __restrict__ g1, const float* __restrict__ be1,
  const float* __restrict__ bk, const float* __restrict__ bv,
  const unsigned short* __restrict__ wf,
  float* __restrict__ g_part, float* __restrict__ g_sump)
{
  __shared__ unsigned short tiles[4][4096];              // 32 KB
  float* ctx_l  = reinterpret_cast<float*>(&tiles[0][0]);   // 64*68 f32 (aliased)
  float* ssum_l = ctx_l + 64*68;                            // 4*64 f32 (aliased)
  const int t = threadIdx.x, wid = t>>6, l = t&63;
  const int lg = l>>4, l15 = l&15;
  unsigned short* tile = tiles[wid];
  const int tok0 = blockIdx.x*256 + wid*64;

  bf16x8 WkF[8], WvF[8];
  #pragma unroll
  for (int f=0; f<8; ++f){
    WkF[f] = ldfrag_g(wf +    0 + f*512 + l*8);
    WvF[f] = ldfrag_g(wf + 8192 + f*512 + l*8);
  }
  float4 g1v  = *reinterpret_cast<const float4*>(&g1[l15*4]);
  float4 be1v = *reinterpret_cast<const float4*>(&be1[l15*4]);
  float bkv[4], bvv[4];
  #pragma unroll
  for (int ct=0; ct<4; ++ct){ bkv[ct]=bk[ct*16+l15]; bvv[ct]=bv[ct*16+l15]; }

  f32x4 acc[4][4];
  #pragma unroll
  for (int a=0;a<4;++a)
    #pragma unroll
    for (int b=0;b<4;++b) acc[a][b] = (f32x4){0.f,0.f,0.f,0.f};
  float sume[4] = {0.f,0.f,0.f,0.f};

  // ---- LN1 of this wave's 64 tokens -> swizzled bf16 tile ----
  #pragma unroll
  for (int it=0; it<16; ++it){
    int row = it*4 + lg;
    float4 xv = *reinterpret_cast<const float4*>(&x[(size_t)(tok0+row)*64 + l15*4]);
    float s1 = xv.x+xv.y+xv.z+xv.w;
    float s2 = xv.x*xv.x + xv.y*xv.y + xv.z*xv.z + xv.w*xv.w;
    #pragma unroll
    for (int off=1; off<16; off<<=1){ s1 += __shfl_xor(s1,off,64); s2 += __shfl_xor(s2,off,64); }
    float mu = s1*(1.f/64.f);
    float rs = rsqrtf(s2*(1.f/64.f) - mu*mu + 1e-5f);
    uint2 pk = { pack2((xv.x-mu)*rs*g1v.x + be1v.x, (xv.y-mu)*rs*g1v.y + be1v.y),
                 pack2((xv.z-mu)*rs*g1v.z + be1v.z, (xv.w-mu)*rs*g1v.w + be1v.w) };
    *reinterpret_cast<uint2*>(&tile[row*64 + ((l15*4) ^ ((row&7)<<3))]) = pk;
  }
  bf16x8 aF[4][2];
  #pragma unroll
  for (int mt=0;mt<4;++mt){
    int row = mt*16+l15, sw=(row&7)<<3, ab=row*64;
    aF[mt][0] = __builtin_bit_cast(bf16x8, *reinterpret_cast<const u16x8*>(tile+ab+((     lg*8)^sw)));
    aF[mt][1] = __builtin_bit_cast(bf16x8, *reinterpret_cast<const u16x8*>(tile+ab+((32 + lg*8)^sw)));
  }
  #pragma unroll
  for (int half=0; half<2; ++half){
    #pragma unroll
    for (int m2=0;m2<2;++m2){
      const int mt = half*2+m2;
      #pragma unroll
      for (int ct=0;ct<4;++ct){
        f32x4 z = {0.f,0.f,0.f,0.f};
        z = mfma16(aF[mt][0], WkF[ct*2+0], z);
        z = mfma16(aF[mt][1], WkF[ct*2+1], z);
        float e0=__expf(z[0]+bkv[ct]), e1=__expf(z[1]+bkv[ct]);
        float e2=__expf(z[2]+bkv[ct]), e3=__expf(z[3]+bkv[ct]);
        sume[ct] += (e0+e1)+(e2+e3);
        const int c = ct*16+l15, sw = (c&7)<<3;
        const int cb = m2*16+lg*4;
        uint2 pe = { pack2(e0,e1), pack2(e2,e3) };
        *reinterpret_cast<uint2*>(&tile[c*64 + (cb ^ sw)]) = pe;
        f32x4 w = {0.f,0.f,0.f,0.f};
        w = mfma16(aF[mt][0], WvF[ct*2+0], w);
        w = mfma16(aF[mt][1], WvF[ct*2+1], w);
        uint2 pv = { pack2(w[0]+bvv[ct], w[1]+bvv[ct]), pack2(w[2]+bvv[ct], w[3]+bvv[ct]) };
        *reinterpret_cast<uint2*>(&tile[c*64 + ((32+cb) ^ sw)]) = pv;
      }
    }
    bf16x8 eA[4], vB[4];
    #pragma unroll
    for (int cm=0;cm<4;++cm){
      int row = cm*16+l15, sw=(row&7)<<3;
      eA[cm] = __builtin_bit_cast(bf16x8, *reinterpret_cast<const u16x8*>(tile + row*64 + ((     lg*8)^sw)));
      vB[cm] = __builtin_bit_cast(bf16x8, *reinterpret_cast<const u16x8*>(tile + row*64 + ((32 + lg*8)^sw)));
    }
    #pragma unroll
    for (int cm=0; cm<4; ++cm)
      #pragma unroll
      for (int jn=0; jn<4; ++jn)
        acc[cm][jn] = mfma16(eA[cm], vB[jn], acc[cm][jn]);
  }

  // ---- all tile reads done: safe to alias tiles as reduction buffers ----
  __syncthreads();
  #pragma unroll
  for (int ct=0; ct<4; ++ct){
    float s = sume[ct];
    s += __shfl_xor(s,16,64); s += __shfl_xor(s,32,64);
    if (lg==0) ssum_l[wid*64 + ct*16+l15] = s;
  }
  #define CTX_RED(OP) \
    _Pragma("unroll") for (int cm=0;cm<4;++cm) \
    _Pragma("unroll") for (int jn=0;jn<4;++jn) \
    _Pragma("unroll") for (int r=0;r<4;++r) \
      ctx_l[(cm*16+lg*4+r)*68 + jn*16+l15] OP acc[cm][jn][r];
  if (wid==0){ CTX_RED(=) }  __syncthreads();
  if (wid==1){ CTX_RED(+=) } __syncthreads();
  if (wid==2){ CTX_RED(+=) } __syncthreads();
  if (wid==3){ CTX_RED(+=) } __syncthreads();
  #undef CTX_RED
  for (int i=t; i<4096; i+=256)
    g_part[(size_t)blockIdx.x*4096 + i] = ctx_l[(i>>6)*68 + (i&63)];
  if (t<64)
    g_sump[blockIdx.x*64 + t] = ssum_l[t] + ssum_l[64+t] + ssum_l[128+t] + ssum_l[192+t];
}

// ============ k15: reduce 64 partials/img; ctxWr = (ctx_norm @ Wr^T) -> bf16 frags ============
__global__ __launch_bounds__(512) void k15_ctxwr(
  const float* __restrict__ g_part, const float* __restrict__ g_sump,
  const float* __restrict__ Wr, unsigned short* __restrict__ ctxWrF)
{
  __shared__ float sctx[4096];
  __shared__ float sWr[4096];
  __shared__ float sinv[64];
  const int b = blockIdx.x, t = threadIdx.x;
  if (t<64){
    float s=0.f;
    #pragma unroll 8
    for (int p=0;p<64;++p) s += g_sump[(b*64+p)*64 + t];
    sinv[t] = 1.f/s;
  }
  for (int idx=t; idx<4096; idx+=512){
    float s=0.f;
    #pragma unroll 8
    for (int p=0;p<64;++p) s += g_part[(size_t)(b*64+p)*4096 + idx];
    sctx[idx] = s;
  }
  __syncthreads();
  {
    int c = t>>3, d0 = (t&7)*8;
    float invc = sinv[c];
    #pragma unroll
    for (int dd=0; dd<8; ++dd){
      int d = d0+dd; float s = 0.f;
      #pragma unroll
      for (int v=0; v<64; ++v) s += sctx[c*64+v]*Wr[d*64+v];
      sWr[c*64+d] = s*invc;
    }
  }
  __syncthreads();
  {
    int f = t>>6, l = t&63, nt = f>>1, ks = f&1;
    u16x8 v;
    #pragma unroll
    for (int j=0;j<8;++j){
      int k = ks*32 + (l>>4)*8 + j;
      int n = nt*16 + (l&15);
      v[j] = f2bf(sWr[k*64+n]);
    }
    *reinterpret_cast<u16x8*>(ctxWrF + b*4096 + f*512 + l*8) = v;
  }
}

// ============ k2: LN1 + q-softmax + attn + residual + LN2 + W1 -> fp8 g_h ============
__global__ __launch_bounds__(256,2) void k2_attn_ffn1(
  const float* __restrict__ x,
  const float* __restrict__ g1, const float* __restrict__ be1,
  const float* __restrict__ bq, const float* __restrict__ br,
  const float* __restrict__ g2, const float* __restrict__ be2,
  const float* __restrict__ b1,
  const unsigned short* __restrict__ wf,
  const unsigned short* __restrict__ ctxWrF,
  unsigned short* __restrict__ g_txb, unsigned char* __restrict__ g_h)
{
  __shared__ unsigned short tiles[4][4096];
  const int t = threadIdx.x, wid = t>>6, l = t&63;
  const int l15 = l&15, lg = l>>4;
  unsigned short* tile = tiles[wid];
  const int tok0 = (blockIdx.x*4 + wid)*64;
  const int img  = blockIdx.x>>6;
  const int yrow = (tok0>>7)&127;
  const int xb   = tok0&127;
  const size_t hbase = ((size_t)(img*128 + yrow)*HPITCH + 1 + xb)*256;  // BYTES (fp8)

  bf16x8 WqF[8], CWF[8];
  #pragma unroll
  for (int f=0; f<8; ++f){
    WqF[f] = ldfrag_g(wf + 4096 + f*512 + l*8);
    CWF[f] = ldfrag_g(ctxWrF + img*4096 + f*512 + l*8);
  }
  float4 g1v  = *reinterpret_cast<const float4*>(&g1[l15*4]);
  float4 be1v = *reinterpret_cast<const float4*>(&be1[l15*4]);
  float bqv[4], brv[4], g2v[4], be2v[4];
  #pragma unroll
  for (int nt=0; nt<4; ++nt){
    bqv[nt]=bq[nt*16+l15]; brv[nt]=br[nt*16+l15];
    g2v[nt]=g2[nt*16+l15]; be2v[nt]=be2[nt*16+l15];
  }
  float b1v[16];
  #pragma unroll
  for (int i=0;i<16;++i) b1v[i]=b1[i*16+l15];

  // ---- LN1 -> swizzled bf16 tile ----
  #pragma unroll
  for (int it=0; it<16; ++it){
    int row = it*4 + lg;
    float4 xv = *reinterpret_cast<const float4*>(&x[(size_t)(tok0+row)*64 + l15*4]);
    float s1 = xv.x+xv.y+xv.z+xv.w;
    float s2 = xv.x*xv.x + xv.y*xv.y + xv.z*xv.z + xv.w*xv.w;
    #pragma unroll
    for (int off=1; off<16; off<<=1){ s1 += __shfl_xor(s1,off,64); s2 += __shfl_xor(s2,off,64); }
    float mu = s1*(1.f/64.f);
    float rs = rsqrtf(s2*(1.f/64.f) - mu*mu + 1e-5f);
    uint2 pk = { pack2((xv.x-mu)*rs*g1v.x + be1v.x, (xv.y-mu)*rs*g1v.y + be1v.y),
                 pack2((xv.z-mu)*rs*g1v.z + be1v.z, (xv.w-mu)*rs*g1v.w + be1v.w) };
    *reinterpret_cast<uint2*>(&tile[row*64 + ((l15*4) ^ ((row&7)<<3))]) = pk;
  }

  // ---- phase A: per m-tile attn chain; leaves n2 in the tile ----
  for (int mt=0; mt<4; ++mt){
    const int arow = mt*16 + l15;
    const int asw  = (arow&7)<<3;
    const int abase= arow*64;
    bf16x8 a0 = __builtin_bit_cast(bf16x8, *reinterpret_cast<const u16x8*>(tile + abase + ((     lg*8) ^ asw)));
    bf16x8 a1 = __builtin_bit_cast(bf16x8, *reinterpret_cast<const u16x8*>(tile + abase + ((32 + lg*8) ^ asw)));
    f32x4 qa[4];
    #pragma unroll
    for (int nt=0; nt<4; ++nt){
      f32x4 z = {0.f,0.f,0.f,0.f};
      z = mfma16(a0, WqF[nt*2+0], z);
      z = mfma16(a1, WqF[nt*2+1], z);
      qa[nt] = z;
    }
    #pragma unroll
    for (int nt=0; nt<4; ++nt)
      #pragma unroll
      for (int r=0; r<4; ++r) qa[nt][r] += bqv[nt];
    float mx[4];
    #pragma unroll
    for (int r=0;r<4;++r) mx[r] = fmaxf(fmaxf(qa[0][r],qa[1][r]), fmaxf(qa[2][r],qa[3][r]));
    #pragma unroll
    for (int off=1; off<16; off<<=1)
      #pragma unroll
      for (int r=0;r<4;++r) mx[r] = fmaxf(mx[r], __shfl_xor(mx[r], off, 64));
    float sm[4] = {0.f,0.f,0.f,0.f};
    #pragma unroll
    for (int nt=0;nt<4;++nt)
      #pragma unroll
      for (int r=0;r<4;++r){ float e = __expf(qa[nt][r]-mx[r]); qa[nt][r]=e; sm[r]+=e; }
    #pragma unroll
    for (int off=1; off<16; off<<=1)
      #pragma unroll
      for (int r=0;r<4;++r) sm[r] += __shfl_xor(sm[r], off, 64);
    float inv[4];
    #pragma unroll
    for (int r=0;r<4;++r) inv[r] = 1.f/sm[r];
    #pragma unroll
    for (int nt=0;nt<4;++nt)
      #pragma unroll
      for (int r=0;r<4;++r){
        int row = mt*16 + lg*4 + r, col = nt*16 + l15;
        tile[row*64 + (col ^ ((row&7)<<3))] = f2bf(qa[nt][r]*inv[r]);
      }
    bf16x8 p0 = __builtin_bit_cast(bf16x8, *reinterpret_cast<const u16x8*>(tile + abase + ((     lg*8) ^ asw)));
    bf16x8 p1 = __builtin_bit_cast(bf16x8, *reinterpret_cast<const u16x8*>(tile + abase + ((32 + lg*8) ^ asw)));
    f32x4 ao[4];
    #pragma unroll
    for (int nt=0; nt<4; ++nt){
      f32x4 z = {0.f,0.f,0.f,0.f};
      z = mfma16(p0, CWF[nt*2+0], z);
      z = mfma16(p1, CWF[nt*2+1], z);
      ao[nt] = z;
    }
    float txv[4][4];
    float s1v[4] = {0.f,0.f,0.f,0.f}, s2v[4] = {0.f,0.f,0.f,0.f};
    #pragma unroll
    for (int nt=0;nt<4;++nt)
      #pragma unroll
      for (int r=0;r<4;++r){
        size_t row = (size_t)(tok0 + mt*16 + lg*4 + r);
        float v = ao[nt][r] + brv[nt] + x[row*64 + nt*16+l15];
        g_txb[row*64 + nt*16+l15] = f2bf(v);
        txv[nt][r] = v; s1v[r] += v; s2v[r] += v*v;
      }
    #pragma unroll
    for (int off=1; off<16; off<<=1)
      #pragma unroll
      for (int r=0;r<4;++r){ s1v[r] += __shfl_xor(s1v[r], off, 64); s2v[r] += __shfl_xor(s2v[r], off, 64); }
    #pragma unroll
    for (int r=0;r<4;++r){
      float mu2 = s1v[r]*(1.f/64.f);
      float rs  = rsqrtf(s2v[r]*(1.f/64.f) - mu2*mu2 + 1e-5f);
      s1v[r] = mu2; s2v[r] = rs;
    }
    #pragma unroll
    for (int nt=0;nt<4;++nt)
      #pragma unroll
      for (int r=0;r<4;++r){
        int row = mt*16 + lg*4 + r, col = nt*16 + l15;
        float n2 = (txv[nt][r]-s1v[r])*s2v[r]*g2v[nt] + be2v[nt];
        tile[row*64 + (col ^ ((row&7)<<3))] = f2bf(n2);
      }
  }

  // ---- phase B: h = n2 @ W1^T + b1; mt-outer, fp8-packed PERMUTED uint4 stores ----
  // channel c = nt2*16 + l15 stored at slot c' = l15*16 + nt2  => 16 contiguous fp8/thread/row.
  for (int mt=0; mt<4; ++mt){
    const int arow = mt*16 + l15;
    const int asw  = (arow&7)<<3;
    const int abase= arow*64;
    bf16x8 n20 = __builtin_bit_cast(bf16x8, *reinterpret_cast<const u16x8*>(tile + abase + ((     lg*8) ^ asw)));
    bf16x8 n21 = __builtin_bit_cast(bf16x8, *reinterpret_cast<const u16x8*>(tile + abase + ((32 + lg*8) ^ asw)));
    unsigned hq[4][4];
    #pragma unroll
    for (int np=0; np<8; ++np){
      bf16x8 wa0 = ldfrag_g(wf + 16384 + (np*4+0)*512 + l*8);
      bf16x8 wa1 = ldfrag_g(wf + 16384 + (np*4+1)*512 + l*8);
      bf16x8 wb0 = ldfrag_g(wf + 16384 + (np*4+2)*512 + l*8);
      bf16x8 wb1 = ldfrag_g(wf + 16384 + (np*4+3)*512 + l*8);
      float ba = b1v[np*2], bb = b1v[np*2+1];
      f32x4 ha = {ba,ba,ba,ba};
      ha = mfma16(n20, wa0, ha);
      ha = mfma16(n21, wa1, ha);
      f32x4 hb = {bb,bb,bb,bb};
      hb = mfma16(n20, wb0, hb);
      hb = mfma16(n21, wb1, hb);
      const int d = np>>1;
      if ((np&1)==0){
        #pragma unroll
        for (int r=0;r<4;++r)
          hq[r][d] = (unsigned)__builtin_amdgcn_cvt_pk_fp8_f32(ha[r], hb[r], 0, false);
      } else {
        #pragma unroll
        for (int r=0;r<4;++r)
          hq[r][d] = (unsigned)__builtin_amdgcn_cvt_pk_fp8_f32(ha[r], hb[r], (int)hq[r][d], true);
      }
    }
    #pragma unroll
    for (int r=0;r<4;++r){
      const size_t ro = hbase + (size_t)(mt*16+lg*4+r)*256 + l15*16;
      uint4 v = { hq[r][0], hq[r][1], hq[r][2], hq[r][3] };
      *reinterpret_cast<uint4*>(g_h + ro) = v;
    }
  }
}

// ============ k3: depthwise conv3x3 + GELU + W2 — fp8 ring, 2ch/lane packed conv ============
// Staging map pi=1+(t>>4), c0=(t&15)*16: global loads contiguous 1KB/wave;
// LDS store banks g+4*(a%8) => exactly 2 lanes/bank (free).
__global__ __launch_bounds__(256,4) void k3_conv_ffn2(
  const unsigned char* __restrict__ g_h,
  const unsigned char* __restrict__ zrow,
  const float* __restrict__ dwp,
  const float* __restrict__ b2,
  const unsigned short* __restrict__ wf,
  const unsigned short* __restrict__ g_txb, float* __restrict__ out)
{
  __shared__ unsigned ring[4][1170];        // 4 slots x 18 pos x 65-dword pitch = 18.7 KB
  __shared__ unsigned short obuf[2][4096];  // double-buffered 16tok x 256ch = 16 KB
  const int t = threadIdx.x, w = t>>6, l = t&63;
  const int l15 = l&15, lg = l>>4;
  const int bid = (blockIdx.x & 7)*128 + (blockIdx.x >> 3);   // XCD-chunked remap
  const int img = bid>>6;
  const int r6  = bid&63;
  const int y0  = (r6>>3)*16, x0 = (r6&7)*16;

  // conv: lane's channel pair cp (slots 2cp, 2cp+1); position group pg
  const int cp = t & 127;
  const int pg = t >> 7;
  f32x2 tp[9];
  #pragma unroll
  for (int j=0;j<9;++j)
    tp[j] = *reinterpret_cast<const f32x2*>(&dwp[cp*24 + j*2]);
  const f32x2 cb2 = *reinterpret_cast<const f32x2*>(&dwp[cp*24 + 18]);

  // W2 frags for output quarter ntc = w
  bf16x8 W2F[8];
  #pragma unroll
  for (int q=0;q<8;++q)
    W2F[q] = ldfrag_g(wf + 32768 + (w*8 + q)*512 + l*8);
  const float4 b2q = *reinterpret_cast<const float4*>(&b2[w*16 + lg*4]);

  // staging map: thread t stages position pi = 1+(t>>4), channels c0..c0+15
  const int pi = 1 + (t>>4);
  const int c0 = (t&15)*16;

  auto rowsrc = [&](int ri) -> const unsigned char* {
    return (ri>=0 && ri<128)
      ? g_h + ((size_t)(img*128+ri)*HPITCH + x0)*256
      : zrow + x0*256;
  };
  auto ldrow = [&](int ri, uint4* m, unsigned* h){
    const unsigned char* src = rowsrc(ri);
    *m = *reinterpret_cast<const uint4*>(src + pi*256 + c0);
    if (t < 128){
      int ph = (t<64)?0:17, dh = t&63;
      *h = reinterpret_cast<const unsigned*>(src + ph*256)[dh];
    }
  };
  auto wrrow = [&](int sl, uint4 m, unsigned h){
    unsigned* rg = ring[sl];
    const int base = pi*65 + (c0>>2);
    rg[base+0] = m.x; rg[base+1] = m.y; rg[base+2] = m.z; rg[base+3] = m.w;
    if (t < 128){
      int ph = (t<64)?0:17, dh = t&63;
      rg[ph*65 + dh] = h;
    }
  };

  // prologue: stage rows y0-1, y0, y0+1 into slots 0,1,2
  {
    uint4 m0,m1,m2; unsigned h0=0,h1=0,h2=0;
    ldrow(y0-1,&m0,&h0); ldrow(y0,&m1,&h1); ldrow(y0+1,&m2,&h2);
    wrrow(0,m0,h0); wrrow(1,m1,h1); wrrow(2,m2,h2);
  }
  __syncthreads();

  const f32x2 kC0 = {-2.3022082f,-2.3022082f};
  const f32x2 kC1 = {-0.1029432f,-0.1029432f};

  for (int yy=0; yy<16; ++yy){
    const int gy = y0 + yy;
    // T14 issue-early: fp8 loads of row gy+2 into regs
    uint4 rm; unsigned rh = 0;
    ldrow(gy+2, &rm, &rh);
    // epilogue residual prefetch
    const size_t gtok = (size_t)img*16384 + (size_t)gy*128 + x0 + l15;
    const u16x4v tq = *reinterpret_cast<const u16x4v*>(&g_txb[gtok*64 + w*16 + lg*4]);

    // conv from fp8 ring (rows y-1,y,y+1 = slots yy, yy+1, yy+2 mod 4)
    {
      const unsigned short* rA = reinterpret_cast<const unsigned short*>(ring[(yy  )&3]);
      const unsigned short* rB = reinterpret_cast<const unsigned short*>(ring[(yy+1)&3]);
      const unsigned short* rC = reinterpret_cast<const unsigned short*>(ring[(yy+2)&3]);
      unsigned short* ob = obuf[yy&1];
      // u16 index for ring position ridx: ridx*130 + cp (2 fp8 = lane's pair)
      const int rb = pg*8;
      f32x2 PA = __builtin_amdgcn_cvt_pk_f32_fp8((int)rA[(rb  )*130 + cp], false);
      f32x2 PB = __builtin_amdgcn_cvt_pk_f32_fp8((int)rB[(rb  )*130 + cp], false);
      f32x2 PC = __builtin_amdgcn_cvt_pk_f32_fp8((int)rC[(rb  )*130 + cp], false);
      f32x2 CA = __builtin_amdgcn_cvt_pk_f32_fp8((int)rA[(rb+1)*130 + cp], false);
      f32x2 CB = __builtin_amdgcn_cvt_pk_f32_fp8((int)rB[(rb+1)*130 + cp], false);
      f32x2 CC = __builtin_amdgcn_cvt_pk_f32_fp8((int)rC[(rb+1)*130 + cp], false);
      #pragma unroll
      for (int i=0;i<8;++i){
        const int ro = (rb+i+2)*130 + cp;
        f32x2 NA = __builtin_amdgcn_cvt_pk_f32_fp8((int)rA[ro], false);
        f32x2 NB = __builtin_amdgcn_cvt_pk_f32_fp8((int)rB[ro], false);
        f32x2 NC = __builtin_amdgcn_cvt_pk_f32_fp8((int)rC[ro], false);
        f32x2 a = cb2;
        a += tp[0]*PA; a += tp[1]*CA; a += tp[2]*NA;
        a += tp[3]*PB; a += tp[4]*CB; a += tp[5]*NB;
        a += tp[6]*PC; a += tp[7]*CC; a += tp[8]*NC;
        f32x2 u = a*a;
        f32x2 wv = u*kC1 + kC0;
        f32x2 arg = a*wv;
        f32x2 e;
        e[0]=__builtin_amdgcn_exp2f(arg[0]); e[1]=__builtin_amdgcn_exp2f(arg[1]);
        f32x2 den = e + (f32x2){1.f,1.f};
        f32x2 rc;
        rc[0]=__builtin_amdgcn_rcpf(den[0]); rc[1]=__builtin_amdgcn_rcpf(den[1]);
        f32x2 g = a*rc;
        unsigned pk;
        asm("v_cvt_pk_bf16_f32 %0, %1, %2" : "=v"(pk) : "v"(g[0]), "v"(g[1]));
        const int p = rb + i;
        *reinterpret_cast<unsigned*>(&ob[p*256 + ((2*cp) ^ ((p&7)<<3))]) = pk;
        PA=CA; PB=CB; PC=CC; CA=NA; CB=NB; CC=NC;
      }
    }

    // write-late: staged fp8 row -> ring slot (yy+3)&3 (raw dwords)
    wrrow((yy+3)&3, rm, rh);
    __syncthreads();

    // W2 MFMA: wave w computes output quarter w over K=256
    f32x4 oacc = {0.f,0.f,0.f,0.f};
    const int nsw = (l15&7)<<3;
    const unsigned short* ob = obuf[yy&1];
    #pragma unroll
    for (int i=0;i<4;++i){
      bf16x8 fb0 = __builtin_bit_cast(bf16x8,
        *reinterpret_cast<const u16x8*>(&ob[l15*256 + ((i*64      + lg*8) ^ nsw)]));
      bf16x8 fb1 = __builtin_bit_cast(bf16x8,
        *reinterpret_cast<const u16x8*>(&ob[l15*256 + ((i*64 + 32 + lg*8) ^ nsw)]));
      oacc = mfma16(W2F[i*2+0], fb0, oacc);
      oacc = mfma16(W2F[i*2+1], fb1, oacc);
    }
    float4 o;
    o.x = oacc[0] + b2q.x + bf2f(tq[0]);
    o.y = oacc[1] + b2q.y + bf2f(tq[1]);
    o.z = oacc[2] + b2q.z + bf2f(tq[2]);
    o.w = oacc[3] + b2q.w + bf2f(tq[3]);
    *reinterpret_cast<float4*>(&out[gtok*64 + w*16 + lg*4]) = o;
  }
}

extern "C" void kernel_launch(void* const* d_in, const int* in_sizes, int n_in,
                              void* d_out, int out_size, void* d_ws, size_t ws_size,
                              hipStream_t stream)
{
  const float* x  =(const float*)d_in[0];
  const float* g1 =(const float*)d_in[3];
  const float* be1=(const float*)d_in[4];
  const float* Wk =(const float*)d_in[5];
  const float* bk =(const float*)d_in[6];
  const float* Wq =(const float*)d_in[7];
  const float* bq =(const float*)d_in[8];
  const float* Wv =(const float*)d_in[9];
  const float* bv =(const float*)d_in[10];
  const float* Wr =(const float*)d_in[11];
  const float* br =(const float*)d_in[12];
  const float* g2 =(const float*)d_in[13];
  const float* be2=(const float*)d_in[14];
  const float* W1 =(const float*)d_in[15];
  const float* b1 =(const float*)d_in[16];
  const float* dww=(const float*)d_in[17];
  const float* dwb=(const float*)d_in[18];
  const float* W2 =(const float*)d_in[19];
  const float* b2 =(const float*)d_in[20];
  float* outp = (float*)d_out;
  char* ws = (char*)d_ws;

  unsigned short* wfb    = (unsigned short*)ws;                 // 96KB
  unsigned short* ctxWrF = (unsigned short*)(ws + 98304);       // 128KB
  float* g_sump = (float*)(ws + 229376);                        // 256KB (1024x64 f32)
  float* g_part = (float*)(ws + 524288);                        // 16.78MB (1024x4096 f32)
  unsigned short* g_txb = (unsigned short*)(ws + 17825792);     // 32MB bf16
  unsigned char* g_h    = (unsigned char*)(ws + 51380224);      // 68.2MB padded fp8
  unsigned char* zr     = (unsigned char*)(ws + 119537664);     // 33KB fp8 zero row
  float* dwp            = (float*)(ws + 119603200);             // 12KB repacked taps+bias

  hipLaunchKernelGGL(k0_wfrag, dim3(97), dim3(64), 0, stream, Wk, Wq, Wv, Wr, W1, W2, dww, dwb, dwp, wfb);
  hipLaunchKernelGGL(zhalo, dim3(1057), dim3(256), 0, stream, (unsigned*)g_h, (unsigned*)zr);
  hipLaunchKernelGGL(k1_ctx, dim3(1024), dim3(256), 0, stream, x, g1, be1, bk, bv, wfb, g_part, g_sump);
  hipLaunchKernelGGL(k15_ctxwr, dim3(16), dim3(512), 0, stream, g_part, g_sump, Wr, ctxWrF);
  hipLaunchKernelGGL(k2_attn_ffn1, dim3(1024), dim3(256), 0, stream,
                     x, g1, be1, bq, br, g2, be2, b1, wfb, ctxWrF, g_txb, g_h);
  hipLaunchKernelGGL(k3_conv_ffn2, dim3(1024), dim3(256), 0, stream,
                     g_h, zr, dwp, b2, wfb, g_txb, outp);
}